// Round 2
// baseline (6748.537 us; speedup 1.0000x reference)
//
#include <hip/hip_runtime.h>
#include <math.h>

#define NL 2
#define KK 3
#define HIDD 64
#define OUTD 32
#define NB 8
#define NN 10000
#define NE 160000
#define ROWS 80000            // NB*NN
#define WSTRIDE (128*HIDD)    // 8192 floats per W[l,d,k] (full 128-row matrix)
#define CHW 64                // feature chunk width
#define RPB 16                // rows per gemm block

// ---------------- setup: zero small arrays ----------------
__global__ void zero_kernel(int* p, long n) {
    long t = (long)blockIdx.x * blockDim.x + threadIdx.x;
    if (t < n) p[t] = 0;
}

// ---------------- degree + CSR counts ----------------
__global__ void deg_cnt_kernel(const float* __restrict__ w, const int* __restrict__ src,
                               const int* __restrict__ dst, float* deg_out, float* deg_in,
                               int* cnt_f, int* cnt_r) {
    int e = blockIdx.x * blockDim.x + threadIdx.x;
    if (e >= NE) return;
    int s = src[e], d = dst[e];
    float we = w[e];
    atomicAdd(&deg_out[s], we);
    atomicAdd(&deg_in[d], we);
    atomicAdd(&cnt_f[d], 1);   // forward CSR keyed by dst
    atomicAdd(&cnt_r[s], 1);   // reverse CSR keyed by src
}

// exclusive scan of NN counts -> off[0..NN], single block of 256 threads
__global__ void scan_kernel(const int* __restrict__ cnt, int* __restrict__ off) {
    __shared__ int part[256];
    const int CH = (NN + 255) / 256;     // 40
    int t = threadIdx.x;
    int s = 0;
    for (int i = 0; i < CH; ++i) {
        int idx = t * CH + i;
        if (idx < NN) s += cnt[idx];
    }
    part[t] = s;
    __syncthreads();
    if (t == 0) {
        int run = 0;
        for (int i = 0; i < 256; ++i) { int v = part[i]; part[i] = run; run += v; }
        off[NN] = run;
    }
    __syncthreads();
    int run = part[t];
    for (int i = 0; i < CH; ++i) {
        int idx = t * CH + i;
        if (idx < NN) { off[idx] = run; run += cnt[idx]; }
    }
}

__global__ void copy_pos_kernel(const int* __restrict__ off_f, const int* __restrict__ off_r,
                                int* pos_f, int* pos_r) {
    int t = blockIdx.x * blockDim.x + threadIdx.x;
    if (t < NN) { pos_f[t] = off_f[t]; pos_r[t] = off_r[t]; }
}

__global__ void fill_kernel(const float* __restrict__ w, const int* __restrict__ src,
                            const int* __restrict__ dst, const float* __restrict__ deg_out,
                            const float* __restrict__ deg_in,
                            int* pos_f, int* pos_r,
                            int* col_f, float* w_f, int* col_r, float* w_r) {
    int e = blockIdx.x * blockDim.x + threadIdx.x;
    if (e >= NE) return;
    int s = src[e], d = dst[e];
    float we = w[e];
    float dgo = deg_out[s]; dgo = (dgo > 0.f) ? dgo : 1.f;
    float dgi = deg_in[d];  dgi = (dgi > 0.f) ? dgi : 1.f;
    int pf = atomicAdd(&pos_f[d], 1);
    col_f[pf] = s; w_f[pf] = we / dgo;   // out[dst] += z[src]*norm_out
    int pr = atomicAdd(&pos_r[s], 1);
    col_r[pr] = d; w_r[pr] = we / dgi;   // out[src] += z[dst]*norm_in
}

// ---------------- CSR gather prop: out = alpha*sum + beta*base ----------------
__global__ __launch_bounds__(256) void gather_prop(
        const float* __restrict__ X, const float* __restrict__ base,
        const int* __restrict__ off, const int* __restrict__ col,
        const float* __restrict__ w, float* __restrict__ out,
        float alpha, float beta) {
    int n = blockIdx.x;
    int t = threadIdx.x;
    int b = blockIdx.y * 4 + (t >> 6);
    int f = t & 63;
    int s = off[n], e = off[n + 1];
    float acc = 0.f;
    for (int j = s; j < e; ++j) {
        int c = col[j];
        float ww = w[j];
        acc = fmaf(X[((long)b * NN + c) * CHW + f], ww, acc);
    }
    long o = ((long)b * NN + n) * CHW + f;
    float v = alpha * acc;
    if (beta != 0.f) v = fmaf(beta, base[o], v);
    out[o] = v;
}

// ---------------- dual-gate GEMM-accumulate stage ----------------
// Zo[row,o] (+)= sum_f X[row,f]*(Wza+Wzb)[f,o]; same for Ro if Wra != null
__global__ __launch_bounds__(256) void gemm_stage(
        const float* __restrict__ X,
        const float* __restrict__ Wza, const float* __restrict__ Wzb,
        const float* __restrict__ Wra, const float* __restrict__ Wrb,
        float* __restrict__ Zo, float* __restrict__ Ro, int init) {
    __shared__ float xs[RPB][CHW];
    __shared__ float wz[CHW][CHW];
    __shared__ float wr[CHW][CHW];
    int t = threadIdx.x;
    for (int i = t; i < CHW * CHW; i += 256) {
        float a = Wza[i];
        if (Wzb) a += Wzb[i];
        wz[i >> 6][i & 63] = a;
    }
    bool dual = (Wra != nullptr);
    if (dual) {
        for (int i = t; i < CHW * CHW; i += 256) {
            float a = Wra[i];
            if (Wrb) a += Wrb[i];
            wr[i >> 6][i & 63] = a;
        }
    }
    long r0 = (long)blockIdx.x * RPB;
    for (int i = t; i < RPB * CHW; i += 256)
        xs[i >> 6][i & 63] = X[(r0 + (i >> 6)) * CHW + (i & 63)];
    __syncthreads();
    int o  = t & 63;
    int rl = t >> 6;
    for (int rr = rl; rr < RPB; rr += 4) {
        float az = 0.f, ar = 0.f;
        #pragma unroll
        for (int f = 0; f < CHW; ++f) {
            float x = xs[rr][f];
            az = fmaf(x, wz[f][o], az);
            if (dual) ar = fmaf(x, wr[f][o], ar);
        }
        long idx = (r0 + rr) * HIDD + o;
        if (init) {
            Zo[idx] = az;
            if (dual) Ro[idx] = ar;
        } else {
            Zo[idx] += az;
            if (dual) Ro[idx] += ar;
        }
    }
}

// ---------------- elementwise finalizes ----------------
__global__ void finalize_zr_kernel(const float* __restrict__ bz, const float* __restrict__ br,
                                   const float* __restrict__ h,
                                   float* __restrict__ Zacc, const float* __restrict__ Racc,
                                   float* __restrict__ rh) {
    long t = (long)blockIdx.x * blockDim.x + threadIdx.x;
    if (t >= (long)ROWS * HIDD) return;
    int j = (int)(t & 63);
    float z = 1.f / (1.f + expf(-(Zacc[t] + bz[j])));
    float r = 1.f / (1.f + expf(-(Racc[t] + br[j])));
    Zacc[t] = z;
    rh[t] = r * h[t];
}

__global__ void finalize_h_kernel(const float* __restrict__ bh, const float* __restrict__ h,
                                  const float* __restrict__ Zg, const float* __restrict__ Hacc,
                                  float* __restrict__ out) {
    long t = (long)blockIdx.x * blockDim.x + threadIdx.x;
    if (t >= (long)ROWS * HIDD) return;
    int j = (int)(t & 63);
    float z = Zg[t];
    float ht = tanhf(Hacc[t] + bh[j]);
    out[t] = z * h[t] + (1.f - z) * ht;
}

// ---------------- final projection 64 -> 32 ----------------
__global__ void proj_kernel(const float* __restrict__ last, const float* __restrict__ W,
                            const float* __restrict__ bias, float* __restrict__ out) {
    long t = (long)blockIdx.x * blockDim.x + threadIdx.x;
    if (t >= (long)ROWS * OUTD) return;
    long row = t >> 5;
    int  o   = (int)(t & 31);
    float acc = bias[o];
    #pragma unroll
    for (int hh = 0; hh < HIDD; ++hh)
        acc = fmaf(last[row * HIDD + hh], W[hh * OUTD + o], acc);
    out[t] = acc;
}

extern "C" void kernel_launch(void* const* d_in, const int* in_sizes, int n_in,
                              void* d_out, int out_size, void* d_ws, size_t ws_size,
                              hipStream_t stream) {
    const float* edge_weight = (const float*)d_in[0];
    const float* hidden      = (const float*)d_in[1];   // [L,B,N,64]
    const float* go_input    = (const float*)d_in[2];   // [B,N,64]
    const float* Wz = (const float*)d_in[3];
    const float* bz = (const float*)d_in[4];
    const float* Wr = (const float*)d_in[5];
    const float* br = (const float*)d_in[6];
    const float* Wh = (const float*)d_in[7];
    const float* bh = (const float*)d_in[8];
    const float* projW = (const float*)d_in[9];
    const float* projb = (const float*)d_in[10];
    const int*   eidx  = (const int*)d_in[11];
    const int* src = eidx;
    const int* dst = eidx + NE;
    float* out = (float*)d_out;

    // ---- workspace layout (4-byte words) ----
    char* wsb = (char*)d_ws;
    size_t need = (size_t)(8 * NN + 2 + 4 * NE) * 4 + (size_t)6 * ROWS * CHW * 4;
    if (ws_size < need) return;   // clean absmax failure signals ws too small

    float* deg_out = (float*)wsb;                 wsb += NN * 4;
    float* deg_in  = (float*)wsb;                 wsb += NN * 4;
    int*   cnt_f   = (int*)wsb;                   wsb += NN * 4;
    int*   cnt_r   = (int*)wsb;                   wsb += NN * 4;
    int*   off_f   = (int*)wsb;                   wsb += (NN + 1) * 4;
    int*   off_r   = (int*)wsb;                   wsb += (NN + 1) * 4;
    int*   pos_f   = (int*)wsb;                   wsb += NN * 4;
    int*   pos_r   = (int*)wsb;                   wsb += NN * 4;
    int*   col_f   = (int*)wsb;                   wsb += NE * 4;
    float* w_f     = (float*)wsb;                 wsb += NE * 4;
    int*   col_r   = (int*)wsb;                   wsb += NE * 4;
    float* w_r     = (float*)wsb;                 wsb += NE * 4;
    float* T1      = (float*)wsb;                 wsb += (long)ROWS * CHW * 4;
    float* T2      = (float*)wsb;                 wsb += (long)ROWS * CHW * 4;
    float* rh      = (float*)wsb;                 wsb += (long)ROWS * CHW * 4;
    float* Zacc    = (float*)wsb;                 wsb += (long)ROWS * CHW * 4;
    float* Racc    = (float*)wsb;                 wsb += (long)ROWS * CHW * 4;   // doubles as Hacc
    float* cur1    = (float*)wsb;                 wsb += (long)ROWS * CHW * 4;

    const int TB = 256;
    const int EGRID = (NE + TB - 1) / TB;
    const int EWGRID = (int)(((long)ROWS * HIDD + TB - 1) / TB);
    const dim3 PGRID(NN, 2);
    const int GGRID = ROWS / RPB;

    // ---- CSR build (once) ----
    zero_kernel<<<(4 * NN + TB - 1) / TB, TB, 0, stream>>>((int*)deg_out, 4 * NN);
    deg_cnt_kernel<<<EGRID, TB, 0, stream>>>(edge_weight, src, dst, deg_out, deg_in, cnt_f, cnt_r);
    scan_kernel<<<1, 256, 0, stream>>>(cnt_f, off_f);
    scan_kernel<<<1, 256, 0, stream>>>(cnt_r, off_r);
    copy_pos_kernel<<<(NN + TB - 1) / TB, TB, 0, stream>>>(off_f, off_r, pos_f, pos_r);
    fill_kernel<<<EGRID, TB, 0, stream>>>(edge_weight, src, dst, deg_out, deg_in,
                                          pos_f, pos_r, col_f, w_f, col_r, w_r);

    const float* cur = go_input;
    for (int l = 0; l < NL; ++l) {
        const float* h = hidden + (long)l * ROWS * HIDD;
        const float* baseZ = Wz + (long)l * 2 * KK * WSTRIDE;
        const float* baseR = Wr + (long)l * 2 * KK * WSTRIDE;
        const float* baseH = Wh + (long)l * 2 * KK * WSTRIDE;

        // term (d,k), chunk c: W slice pointer (64x64 contiguous rows)
        auto wp = [&](const float* base, int d, int k, int c) {
            return base + (long)(d * KK + k) * WSTRIDE + (long)c * CHW * HIDD;
        };

        // ---- Z/R accumulation over 2 feature chunks ----
        for (int c = 0; c < 2; ++c) {
            const float* X0 = (c == 0) ? cur : h;
            gemm_stage<<<GGRID, 256, 0, stream>>>(X0,
                wp(baseZ,0,0,c), wp(baseZ,1,0,c), wp(baseR,0,0,c), wp(baseR,1,0,c),
                Zacc, Racc, (c == 0) ? 1 : 0);
            gather_prop<<<PGRID, 256, 0, stream>>>(X0, nullptr, off_f, col_f, w_f, T1, 1.f, 0.f);
            gemm_stage<<<GGRID, 256, 0, stream>>>(T1,
                wp(baseZ,0,1,c), nullptr, wp(baseR,0,1,c), nullptr, Zacc, Racc, 0);
            gather_prop<<<PGRID, 256, 0, stream>>>(T1, X0, off_f, col_f, w_f, T2, 2.f, -1.f);
            gemm_stage<<<GGRID, 256, 0, stream>>>(T2,
                wp(baseZ,0,2,c), nullptr, wp(baseR,0,2,c), nullptr, Zacc, Racc, 0);
            gather_prop<<<PGRID, 256, 0, stream>>>(X0, nullptr, off_r, col_r, w_r, T1, 1.f, 0.f);
            gemm_stage<<<GGRID, 256, 0, stream>>>(T1,
                wp(baseZ,1,1,c), nullptr, wp(baseR,1,1,c), nullptr, Zacc, Racc, 0);
            gather_prop<<<PGRID, 256, 0, stream>>>(T1, X0, off_r, col_r, w_r, T2, 2.f, -1.f);
            gemm_stage<<<GGRID, 256, 0, stream>>>(T2,
                wp(baseZ,1,2,c), nullptr, wp(baseR,1,2,c), nullptr, Zacc, Racc, 0);
        }
        // Z = sigmoid(Zacc+bz) (in place), rh = sigmoid(Racc+br)*h
        finalize_zr_kernel<<<EWGRID, TB, 0, stream>>>(bz + l * HIDD, br + l * HIDD, h,
                                                      Zacc, Racc, rh);

        // ---- H accumulation (Hacc aliases Racc) ----
        float* Hacc = Racc;
        for (int c = 0; c < 2; ++c) {
            const float* X0 = (c == 0) ? cur : rh;
            gemm_stage<<<GGRID, 256, 0, stream>>>(X0,
                wp(baseH,0,0,c), wp(baseH,1,0,c), nullptr, nullptr,
                Hacc, nullptr, (c == 0) ? 1 : 0);
            gather_prop<<<PGRID, 256, 0, stream>>>(X0, nullptr, off_f, col_f, w_f, T1, 1.f, 0.f);
            gemm_stage<<<GGRID, 256, 0, stream>>>(T1,
                wp(baseH,0,1,c), nullptr, nullptr, nullptr, Hacc, nullptr, 0);
            gather_prop<<<PGRID, 256, 0, stream>>>(T1, X0, off_f, col_f, w_f, T2, 2.f, -1.f);
            gemm_stage<<<GGRID, 256, 0, stream>>>(T2,
                wp(baseH,0,2,c), nullptr, nullptr, nullptr, Hacc, nullptr, 0);
            gather_prop<<<PGRID, 256, 0, stream>>>(X0, nullptr, off_r, col_r, w_r, T1, 1.f, 0.f);
            gemm_stage<<<GGRID, 256, 0, stream>>>(T1,
                wp(baseH,1,1,c), nullptr, nullptr, nullptr, Hacc, nullptr, 0);
            gather_prop<<<PGRID, 256, 0, stream>>>(T1, X0, off_r, col_r, w_r, T2, 2.f, -1.f);
            gemm_stage<<<GGRID, 256, 0, stream>>>(T2,
                wp(baseH,1,2,c), nullptr, nullptr, nullptr, Hacc, nullptr, 0);
        }
        // out = Z*h + (1-Z)*tanh(Hacc+bh); layer0 -> cur1, layer1 -> Zacc (in-place safe)
        float* outl = (l == 0) ? cur1 : Zacc;
        finalize_h_kernel<<<EWGRID, TB, 0, stream>>>(bh + l * HIDD, h, Zacc, Hacc, outl);
        cur = outl;
    }

    proj_kernel<<<(int)(((long)ROWS * OUTD + TB - 1) / TB), TB, 0, stream>>>(
        Zacc, projW, projb, out);
}

// Round 3
// 2451.369 us; speedup vs baseline: 2.7530x; 2.7530x over previous
//
#include <hip/hip_runtime.h>
#include <math.h>

#define NL 2
#define KK 3
#define HIDD 64
#define OUTD 32
#define NB 8
#define NN 10000
#define NE 160000
#define ROWS 80000            // NB*NN
#define WSTRIDE (128*HIDD)    // 8192 floats per W[l,d,k]

// ---------------- setup: zero small arrays ----------------
__global__ void zero_kernel(int* p, long n) {
    long t = (long)blockIdx.x * blockDim.x + threadIdx.x;
    if (t < n) p[t] = 0;
}

// ---------------- degree + CSR counts ----------------
__global__ void deg_cnt_kernel(const float* __restrict__ w, const int* __restrict__ src,
                               const int* __restrict__ dst, float* deg_out, float* deg_in,
                               int* cnt_f, int* cnt_r) {
    int e = blockIdx.x * blockDim.x + threadIdx.x;
    if (e >= NE) return;
    int s = src[e], d = dst[e];
    float we = w[e];
    atomicAdd(&deg_out[s], we);
    atomicAdd(&deg_in[d], we);
    atomicAdd(&cnt_f[d], 1);   // forward CSR keyed by dst
    atomicAdd(&cnt_r[s], 1);   // reverse CSR keyed by src
}

// exclusive scan of NN counts -> off[0..NN], single block of 256 threads
__global__ void scan_kernel(const int* __restrict__ cnt, int* __restrict__ off) {
    __shared__ int part[256];
    const int CH = (NN + 255) / 256;     // 40
    int t = threadIdx.x;
    int s = 0;
    for (int i = 0; i < CH; ++i) {
        int idx = t * CH + i;
        if (idx < NN) s += cnt[idx];
    }
    part[t] = s;
    __syncthreads();
    if (t == 0) {
        int run = 0;
        for (int i = 0; i < 256; ++i) { int v = part[i]; part[i] = run; run += v; }
        off[NN] = run;
    }
    __syncthreads();
    int run = part[t];
    for (int i = 0; i < CH; ++i) {
        int idx = t * CH + i;
        if (idx < NN) { off[idx] = run; run += cnt[idx]; }
    }
}

__global__ void copy_pos_kernel(const int* __restrict__ off_f, const int* __restrict__ off_r,
                                int* pos_f, int* pos_r) {
    int t = blockIdx.x * blockDim.x + threadIdx.x;
    if (t < NN) { pos_f[t] = off_f[t]; pos_r[t] = off_r[t]; }
}

__global__ void fill_kernel(const float* __restrict__ w, const int* __restrict__ src,
                            const int* __restrict__ dst, const float* __restrict__ deg_out,
                            const float* __restrict__ deg_in,
                            int* pos_f, int* pos_r,
                            int* col_f, float* w_f, int* col_r, float* w_r) {
    int e = blockIdx.x * blockDim.x + threadIdx.x;
    if (e >= NE) return;
    int s = src[e], d = dst[e];
    float we = w[e];
    float dgo = deg_out[s]; dgo = (dgo > 0.f) ? dgo : 1.f;
    float dgi = deg_in[d];  dgi = (dgi > 0.f) ? dgi : 1.f;
    int pf = atomicAdd(&pos_f[d], 1);
    col_f[pf] = s; w_f[pf] = we / dgo;   // out[dst] += z[src]*norm_out
    int pr = atomicAdd(&pos_r[s], 1);
    col_r[pr] = d; w_r[pr] = we / dgi;   // out[src] += z[dst]*norm_in
}

// ---------------- CSR gather prop (float4): out = alpha*sum + beta*base ----------------
__global__ __launch_bounds__(128) void gather_prop(
        const float4* __restrict__ X, const float4* __restrict__ base,
        const int* __restrict__ off, const int* __restrict__ col,
        const float* __restrict__ w, float4* __restrict__ out,
        float alpha, float beta) {
    int n = blockIdx.x;
    int t = threadIdx.x;
    int b  = t >> 4;        // 0..7
    int fq = t & 15;        // 16 float4 quads = 64 features
    int s = off[n], e = off[n + 1];
    float ax = 0.f, ay = 0.f, az = 0.f, aw = 0.f;
    for (int j = s; j < e; ++j) {
        int c = col[j];
        float ww = w[j];
        float4 v = X[((long)b * NN + c) * 16 + fq];
        ax = fmaf(v.x, ww, ax); ay = fmaf(v.y, ww, ay);
        az = fmaf(v.z, ww, az); aw = fmaf(v.w, ww, aw);
    }
    long o = ((long)b * NN + n) * 16 + fq;
    float4 r;
    r.x = alpha * ax; r.y = alpha * ay; r.z = alpha * az; r.w = alpha * aw;
    if (beta != 0.f) {
        float4 bb = base[o];
        r.x = fmaf(beta, bb.x, r.x); r.y = fmaf(beta, bb.y, r.y);
        r.z = fmaf(beta, bb.z, r.z); r.w = fmaf(beta, bb.w, r.w);
    }
    out[o] = r;
}

// ---------------- register-tiled multi-term GEMM ----------------
// Z[row,c] (+)= sum_t X_t[row,:] @ W0_t[:,c]   (and R with W1_t if DUAL)
// term 0 may have a second W added (the k=0 term summed over both directions).
struct GArgs {
    const float* X[5];
    const float* W0[5];
    const float* W1[5];
    const float* W0b;
    const float* W1b;
    int nt;
    int accum;
};

template<int DUAL>
__global__ __launch_bounds__(128) void gemm_multi(GArgs A, float* __restrict__ Z,
                                                  float* __restrict__ R) {
    constexpr int BR  = DUAL ? 64 : 128;   // rows per block
    constexpr int NCG = DUAL ? 16 : 8;     // col groups (8 cols each)
    __shared__ float xs[BR][65];
    __shared__ float ws[64][DUAL ? 132 : 72];
    int t = threadIdx.x;
    int cg = t % NCG;
    int rg = t / NCG;
    int c0 = cg * 8;
    int r0 = rg * 8;
    long grow0 = (long)blockIdx.x * BR;
    float acc[8][8];
    #pragma unroll
    for (int i = 0; i < 8; ++i)
        #pragma unroll
        for (int j = 0; j < 8; ++j) acc[i][j] = 0.f;

    for (int tt = 0; tt < A.nt; ++tt) {
        __syncthreads();
        // ---- load X tile (float4 global, scalar LDS stores) ----
        const float4* X4 = (const float4*)A.X[tt];
        for (int i = t; i < BR * 16; i += 128) {
            int row = i >> 4, q = i & 15;
            float4 v = X4[(grow0 + row) * 16 + q];
            xs[row][4*q+0] = v.x; xs[row][4*q+1] = v.y;
            xs[row][4*q+2] = v.z; xs[row][4*q+3] = v.w;
        }
        // ---- load W tile(s) ----
        const float4* W4 = (const float4*)A.W0[tt];
        const float4* W4b = (tt == 0 && A.W0b) ? (const float4*)A.W0b : nullptr;
        for (int i = t; i < 1024; i += 128) {
            int row = i >> 4, q = i & 15;
            float4 v = W4[row * 16 + q];
            if (W4b) {
                float4 u = W4b[row * 16 + q];
                v.x += u.x; v.y += u.y; v.z += u.z; v.w += u.w;
            }
            ws[row][4*q+0] = v.x; ws[row][4*q+1] = v.y;
            ws[row][4*q+2] = v.z; ws[row][4*q+3] = v.w;
        }
        if (DUAL) {
            const float4* V4 = (const float4*)A.W1[tt];
            const float4* V4b = (tt == 0 && A.W1b) ? (const float4*)A.W1b : nullptr;
            for (int i = t; i < 1024; i += 128) {
                int row = i >> 4, q = i & 15;
                float4 v = V4[row * 16 + q];
                if (V4b) {
                    float4 u = V4b[row * 16 + q];
                    v.x += u.x; v.y += u.y; v.z += u.z; v.w += u.w;
                }
                ws[row][64 + 4*q+0] = v.x; ws[row][64 + 4*q+1] = v.y;
                ws[row][64 + 4*q+2] = v.z; ws[row][64 + 4*q+3] = v.w;
            }
        }
        __syncthreads();
        // ---- 8x8 register micro-tile over K=64 ----
        #pragma unroll 4
        for (int f = 0; f < 64; ++f) {
            float xr[8];
            #pragma unroll
            for (int i = 0; i < 8; ++i) xr[i] = xs[r0 + i][f];
            float4 w0 = *(const float4*)&ws[f][c0];
            float4 w1 = *(const float4*)&ws[f][c0 + 4];
            #pragma unroll
            for (int i = 0; i < 8; ++i) {
                acc[i][0] = fmaf(xr[i], w0.x, acc[i][0]);
                acc[i][1] = fmaf(xr[i], w0.y, acc[i][1]);
                acc[i][2] = fmaf(xr[i], w0.z, acc[i][2]);
                acc[i][3] = fmaf(xr[i], w0.w, acc[i][3]);
                acc[i][4] = fmaf(xr[i], w1.x, acc[i][4]);
                acc[i][5] = fmaf(xr[i], w1.y, acc[i][5]);
                acc[i][6] = fmaf(xr[i], w1.z, acc[i][6]);
                acc[i][7] = fmaf(xr[i], w1.w, acc[i][7]);
            }
        }
    }
    // ---- epilogue ----
    float* outp = (DUAL && cg >= 8) ? R : Z;
    int lc = c0 & 63;
    #pragma unroll
    for (int i = 0; i < 8; ++i) {
        long base = (grow0 + r0 + i) * HIDD + lc;
        float4 v0 = make_float4(acc[i][0], acc[i][1], acc[i][2], acc[i][3]);
        float4 v1 = make_float4(acc[i][4], acc[i][5], acc[i][6], acc[i][7]);
        if (A.accum) {
            float4 o0 = *(const float4*)&outp[base];
            float4 o1 = *(const float4*)&outp[base + 4];
            v0.x += o0.x; v0.y += o0.y; v0.z += o0.z; v0.w += o0.w;
            v1.x += o1.x; v1.y += o1.y; v1.z += o1.z; v1.w += o1.w;
        }
        *(float4*)&outp[base] = v0;
        *(float4*)&outp[base + 4] = v1;
    }
}

// ---------------- elementwise finalizes ----------------
// Zacc <- sigmoid(Zacc+bz); Racc <- sigmoid(Racc+br)*h   (rh in place)
__global__ void finalize_zr_kernel(const float* __restrict__ bz, const float* __restrict__ br,
                                   const float* __restrict__ h,
                                   float* __restrict__ Zacc, float* __restrict__ Racc) {
    long t = (long)blockIdx.x * blockDim.x + threadIdx.x;
    if (t >= (long)ROWS * HIDD) return;
    int j = (int)(t & 63);
    float z = 1.f / (1.f + expf(-(Zacc[t] + bz[j])));
    float r = 1.f / (1.f + expf(-(Racc[t] + br[j])));
    Zacc[t] = z;
    Racc[t] = r * h[t];
}

__global__ void finalize_h_kernel(const float* __restrict__ bh, const float* __restrict__ h,
                                  const float* __restrict__ Zg, const float* __restrict__ Hacc,
                                  float* __restrict__ out) {
    long t = (long)blockIdx.x * blockDim.x + threadIdx.x;
    if (t >= (long)ROWS * HIDD) return;
    int j = (int)(t & 63);
    float z = Zg[t];
    float ht = tanhf(Hacc[t] + bh[j]);
    out[t] = z * h[t] + (1.f - z) * ht;
}

// ---------------- final projection 64 -> 32 ----------------
__global__ void proj_kernel(const float* __restrict__ last, const float* __restrict__ W,
                            const float* __restrict__ bias, float* __restrict__ out) {
    long t = (long)blockIdx.x * blockDim.x + threadIdx.x;
    if (t >= (long)ROWS * OUTD) return;
    long row = t >> 5;
    int  o   = (int)(t & 31);
    float acc = bias[o];
    #pragma unroll
    for (int hh = 0; hh < HIDD; ++hh)
        acc = fmaf(last[row * HIDD + hh], W[hh * OUTD + o], acc);
    out[t] = acc;
}

extern "C" void kernel_launch(void* const* d_in, const int* in_sizes, int n_in,
                              void* d_out, int out_size, void* d_ws, size_t ws_size,
                              hipStream_t stream) {
    const float* edge_weight = (const float*)d_in[0];
    const float* hidden      = (const float*)d_in[1];   // [L,B,N,64]
    const float* go_input    = (const float*)d_in[2];   // [B,N,64]
    const float* Wz = (const float*)d_in[3];
    const float* bz = (const float*)d_in[4];
    const float* Wr = (const float*)d_in[5];
    const float* br = (const float*)d_in[6];
    const float* Wh = (const float*)d_in[7];
    const float* bh = (const float*)d_in[8];
    const float* projW = (const float*)d_in[9];
    const float* projb = (const float*)d_in[10];
    const int*   eidx  = (const int*)d_in[11];
    const int* src = eidx;
    const int* dst = eidx + NE;
    float* out = (float*)d_out;

    // ---- workspace layout (16B-aligned pieces) ----
    char* p = (char*)d_ws;
    auto alloc = [&](size_t bytes) { char* r = p; p += (bytes + 15) & ~(size_t)15; return r; };
    float* deg_out = (float*)alloc(NN * 4);
    float* deg_in  = (float*)alloc(NN * 4);
    int*   cnt_f   = (int*)alloc(NN * 4);
    int*   cnt_r   = (int*)alloc(NN * 4);
    int*   off_f   = (int*)alloc((NN + 4) * 4);
    int*   off_r   = (int*)alloc((NN + 4) * 4);
    int*   pos_f   = (int*)alloc(NN * 4);
    int*   pos_r   = (int*)alloc(NN * 4);
    int*   col_f   = (int*)alloc(NE * 4);
    float* w_f     = (float*)alloc(NE * 4);
    int*   col_r   = (int*)alloc(NE * 4);
    float* w_r     = (float*)alloc(NE * 4);
    size_t csr_bytes = (size_t)(p - (char*)d_ws);
    const size_t BUFB = (size_t)ROWS * HIDD * 4;   // 20.48 MB

    bool shared_ok = ws_size >= csr_bytes + 8 * BUFB;
    float* T1f = (float*)alloc(BUFB);
    float* T2f = (float*)alloc(BUFB);
    float* T1r = nullptr; float* T2r = nullptr;
    if (shared_ok) { T1r = (float*)alloc(BUFB); T2r = (float*)alloc(BUFB); }
    float* Zacc = (float*)alloc(BUFB);
    float* Racc = (float*)alloc(BUFB);   // becomes rh after finalize_zr
    float* Hacc = (float*)alloc(BUFB);
    float* cur1 = (float*)alloc(BUFB);
    if ((size_t)(p - (char*)d_ws) > ws_size) return;   // ws too small: clean fail

    const int TB = 256;
    const int EGRID = (NE + TB - 1) / TB;
    const int EWGRID = (int)(((long)ROWS * HIDD + TB - 1) / TB);

    // ---- CSR build (once) ----
    zero_kernel<<<(4 * NN + TB - 1) / TB, TB, 0, stream>>>((int*)deg_out, 4 * NN);
    deg_cnt_kernel<<<EGRID, TB, 0, stream>>>(edge_weight, src, dst, deg_out, deg_in, cnt_f, cnt_r);
    scan_kernel<<<1, 256, 0, stream>>>(cnt_f, off_f);
    scan_kernel<<<1, 256, 0, stream>>>(cnt_r, off_r);
    copy_pos_kernel<<<(NN + TB - 1) / TB, TB, 0, stream>>>(off_f, off_r, pos_f, pos_r);
    fill_kernel<<<EGRID, TB, 0, stream>>>(edge_weight, src, dst, deg_out, deg_in,
                                          pos_f, pos_r, col_f, w_f, col_r, w_r);

    auto wslice = [&](const float* Wb, int l, int d, int k, int c) {
        return Wb + (((long)l * 2 + d) * KK + k) * WSTRIDE + (long)c * 64 * 64;
    };
    auto prop = [&](const float* X, const float* base, const int* off, const int* col,
                    const float* w, float* o, float alpha, float beta) {
        gather_prop<<<NN, 128, 0, stream>>>((const float4*)X, (const float4*)base,
                                            off, col, w, (float4*)o, alpha, beta);
    };

    const float* cur = go_input;
    for (int l = 0; l < NL; ++l) {
        const float* h = hidden + (long)l * ROWS * HIDD;

        if (shared_ok) {
            // ---- chunk-0 diffusion of cur (shared by Z, R, H) ----
            prop(cur, nullptr, off_f, col_f, w_f, T1f, 1.f, 0.f);
            prop(T1f, cur,     off_f, col_f, w_f, T2f, 2.f, -1.f);
            prop(cur, nullptr, off_r, col_r, w_r, T1r, 1.f, 0.f);
            prop(T1r, cur,     off_r, col_r, w_r, T2r, 2.f, -1.f);

            auto terms5 = [&](const float* Wg, const float* X0, int c, GArgs& a) {
                a.X[0] = X0;  a.W0[0] = wslice(Wg, l, 0, 0, c);
                a.X[1] = T1f; a.W0[1] = wslice(Wg, l, 0, 1, c);
                a.X[2] = T2f; a.W0[2] = wslice(Wg, l, 0, 2, c);
                a.X[3] = T1r; a.W0[3] = wslice(Wg, l, 1, 1, c);
                a.X[4] = T2r; a.W0[4] = wslice(Wg, l, 1, 2, c);
                a.nt = 5;
            };
            GArgs a{};
            // Z/R chunk-0 (init)
            terms5(Wz, cur, 0, a);
            a.W0b = wslice(Wz, l, 1, 0, 0);
            for (int i = 0; i < 5; ++i) a.W1[i] = wslice(Wr, l, i<1?0:(i<3?0:1), i==0?0:(i==1?1:(i==2?2:(i==3?1:2))), 0);
            // (explicit, readable version:)
            a.W1[0] = wslice(Wr, l, 0, 0, 0); a.W1[1] = wslice(Wr, l, 0, 1, 0);
            a.W1[2] = wslice(Wr, l, 0, 2, 0); a.W1[3] = wslice(Wr, l, 1, 1, 0);
            a.W1[4] = wslice(Wr, l, 1, 2, 0);
            a.W1b = wslice(Wr, l, 1, 0, 0);
            a.accum = 0;
            gemm_multi<1><<<ROWS / 64, 128, 0, stream>>>(a, Zacc, Racc);
            // H chunk-0 (init)
            GArgs ah{};
            terms5(Wh, cur, 0, ah);
            ah.W0b = wslice(Wh, l, 1, 0, 0);
            ah.accum = 0;
            gemm_multi<0><<<ROWS / 128, 128, 0, stream>>>(ah, Hacc, nullptr);

            // ---- chunk-1 diffusion of h ----
            prop(h, nullptr, off_f, col_f, w_f, T1f, 1.f, 0.f);
            prop(T1f, h,     off_f, col_f, w_f, T2f, 2.f, -1.f);
            prop(h, nullptr, off_r, col_r, w_r, T1r, 1.f, 0.f);
            prop(T1r, h,     off_r, col_r, w_r, T2r, 2.f, -1.f);
            GArgs a1{};
            terms5(Wz, h, 1, a1);
            a1.W0b = wslice(Wz, l, 1, 0, 1);
            a1.W1[0] = wslice(Wr, l, 0, 0, 1); a1.W1[1] = wslice(Wr, l, 0, 1, 1);
            a1.W1[2] = wslice(Wr, l, 0, 2, 1); a1.W1[3] = wslice(Wr, l, 1, 1, 1);
            a1.W1[4] = wslice(Wr, l, 1, 2, 1);
            a1.W1b = wslice(Wr, l, 1, 0, 1);
            a1.accum = 1;
            gemm_multi<1><<<ROWS / 64, 128, 0, stream>>>(a1, Zacc, Racc);

            finalize_zr_kernel<<<EWGRID, TB, 0, stream>>>(bz + l * HIDD, br + l * HIDD, h,
                                                          Zacc, Racc);
            const float* rh = Racc;
            // ---- chunk-1 diffusion of rh ----
            prop(rh, nullptr, off_f, col_f, w_f, T1f, 1.f, 0.f);
            prop(T1f, rh,     off_f, col_f, w_f, T2f, 2.f, -1.f);
            prop(rh, nullptr, off_r, col_r, w_r, T1r, 1.f, 0.f);
            prop(T1r, rh,     off_r, col_r, w_r, T2r, 2.f, -1.f);
            GArgs ah1{};
            terms5(Wh, rh, 1, ah1);
            ah1.W0b = wslice(Wh, l, 1, 0, 1);
            ah1.accum = 1;
            gemm_multi<0><<<ROWS / 128, 128, 0, stream>>>(ah1, Hacc, nullptr);
        } else {
            // ---- fallback: 2 T-buffers, re-diffuse cur for H ----
            auto zr_chunk = [&](const float* X0, int c) {
                prop(X0, nullptr, off_f, col_f, w_f, T1f, 1.f, 0.f);
                prop(T1f, X0,     off_f, col_f, w_f, T2f, 2.f, -1.f);
                GArgs a{};
                a.X[0] = X0;  a.W0[0] = wslice(Wz, l, 0, 0, c); a.W1[0] = wslice(Wr, l, 0, 0, c);
                a.X[1] = T1f; a.W0[1] = wslice(Wz, l, 0, 1, c); a.W1[1] = wslice(Wr, l, 0, 1, c);
                a.X[2] = T2f; a.W0[2] = wslice(Wz, l, 0, 2, c); a.W1[2] = wslice(Wr, l, 0, 2, c);
                a.W0b = wslice(Wz, l, 1, 0, c); a.W1b = wslice(Wr, l, 1, 0, c);
                a.nt = 3; a.accum = (c == 0) ? 0 : 1;
                gemm_multi<1><<<ROWS / 64, 128, 0, stream>>>(a, Zacc, Racc);
                prop(X0, nullptr, off_r, col_r, w_r, T1f, 1.f, 0.f);
                prop(T1f, X0,     off_r, col_r, w_r, T2f, 2.f, -1.f);
                GArgs b{};
                b.X[0] = T1f; b.W0[0] = wslice(Wz, l, 1, 1, c); b.W1[0] = wslice(Wr, l, 1, 1, c);
                b.X[1] = T2f; b.W0[1] = wslice(Wz, l, 1, 2, c); b.W1[1] = wslice(Wr, l, 1, 2, c);
                b.nt = 2; b.accum = 1;
                gemm_multi<1><<<ROWS / 64, 128, 0, stream>>>(b, Zacc, Racc);
            };
            zr_chunk(cur, 0);
            zr_chunk(h, 1);
            finalize_zr_kernel<<<EWGRID, TB, 0, stream>>>(bz + l * HIDD, br + l * HIDD, h,
                                                          Zacc, Racc);
            auto h_chunk = [&](const float* X0, int c) {
                prop(X0, nullptr, off_f, col_f, w_f, T1f, 1.f, 0.f);
                prop(T1f, X0,     off_f, col_f, w_f, T2f, 2.f, -1.f);
                GArgs a{};
                a.X[0] = X0;  a.W0[0] = wslice(Wh, l, 0, 0, c);
                a.X[1] = T1f; a.W0[1] = wslice(Wh, l, 0, 1, c);
                a.X[2] = T2f; a.W0[2] = wslice(Wh, l, 0, 2, c);
                a.W0b = wslice(Wh, l, 1, 0, c);
                a.nt = 3; a.accum = (c == 0) ? 0 : 1;
                gemm_multi<0><<<ROWS / 128, 128, 0, stream>>>(a, Hacc, nullptr);
                prop(X0, nullptr, off_r, col_r, w_r, T1f, 1.f, 0.f);
                prop(T1f, X0,     off_r, col_r, w_r, T2f, 2.f, -1.f);
                GArgs b{};
                b.X[0] = T1f; b.W0[0] = wslice(Wh, l, 1, 1, c);
                b.X[1] = T2f; b.W0[1] = wslice(Wh, l, 1, 2, c);
                b.nt = 2; b.accum = 1;
                gemm_multi<0><<<ROWS / 128, 128, 0, stream>>>(b, Hacc, nullptr);
            };
            h_chunk(cur, 0);
            h_chunk(Racc, 1);   // Racc holds rh
        }

        float* outl = (l == 0) ? cur1 : Zacc;   // l==1: in-place over Z (elementwise-safe)
        finalize_h_kernel<<<EWGRID, TB, 0, stream>>>(bh + l * HIDD, h, Zacc, Hacc, outl);
        cur = outl;
    }

    proj_kernel<<<(int)(((long)ROWS * OUTD + TB - 1) / TB), TB, 0, stream>>>(
        cur, projW, projb, out);
}

// Round 4
// 1377.385 us; speedup vs baseline: 4.8995x; 1.7797x over previous
//
#include <hip/hip_runtime.h>
#include <math.h>

#define NL 2
#define KK 3
#define HIDD 64
#define OUTD 32
#define NB 8
#define NN 10000
#define NE 160000
#define ROWS 80000            // NB*NN
#define WSTRIDE (128*HIDD)    // 8192 floats per W[l,d,k]

typedef __attribute__((ext_vector_type(8))) short bf16x8;
typedef __attribute__((ext_vector_type(4))) float f32x4;

__device__ __forceinline__ ushort f2b(float x) {
    union { float f; unsigned u; } v; v.f = x;
    unsigned r = (v.u + 0x7fff + ((v.u >> 16) & 1)) >> 16;
    return (ushort)r;
}
__device__ __forceinline__ float b2f(ushort u) {
    union { unsigned u; float f; } v; v.u = (unsigned)u << 16;
    return v.f;
}

// ---------------- setup: zero small arrays ----------------
__global__ void zero_kernel(int* p, long n) {
    long t = (long)blockIdx.x * blockDim.x + threadIdx.x;
    if (t < n) p[t] = 0;
}

// ---------------- degree + CSR counts ----------------
__global__ void deg_cnt_kernel(const float* __restrict__ w, const int* __restrict__ src,
                               const int* __restrict__ dst, float* deg_out, float* deg_in,
                               int* cnt_f, int* cnt_r) {
    int e = blockIdx.x * blockDim.x + threadIdx.x;
    if (e >= NE) return;
    int s = src[e], d = dst[e];
    float we = w[e];
    atomicAdd(&deg_out[s], we);
    atomicAdd(&deg_in[d], we);
    atomicAdd(&cnt_f[d], 1);
    atomicAdd(&cnt_r[s], 1);
}

__global__ void scan_kernel(const int* __restrict__ cnt, int* __restrict__ off) {
    __shared__ int part[256];
    const int CH = (NN + 255) / 256;
    int t = threadIdx.x;
    int s = 0;
    for (int i = 0; i < CH; ++i) {
        int idx = t * CH + i;
        if (idx < NN) s += cnt[idx];
    }
    part[t] = s;
    __syncthreads();
    if (t == 0) {
        int run = 0;
        for (int i = 0; i < 256; ++i) { int v = part[i]; part[i] = run; run += v; }
        off[NN] = run;
    }
    __syncthreads();
    int run = part[t];
    for (int i = 0; i < CH; ++i) {
        int idx = t * CH + i;
        if (idx < NN) { off[idx] = run; run += cnt[idx]; }
    }
}

__global__ void copy_pos_kernel(const int* __restrict__ off_f, const int* __restrict__ off_r,
                                int* pos_f, int* pos_r) {
    int t = blockIdx.x * blockDim.x + threadIdx.x;
    if (t < NN) { pos_f[t] = off_f[t]; pos_r[t] = off_r[t]; }
}

__global__ void fill_kernel(const float* __restrict__ w, const int* __restrict__ src,
                            const int* __restrict__ dst, const float* __restrict__ deg_out,
                            const float* __restrict__ deg_in,
                            int* pos_f, int* pos_r,
                            int* col_f, float* w_f, int* col_r, float* w_r) {
    int e = blockIdx.x * blockDim.x + threadIdx.x;
    if (e >= NE) return;
    int s = src[e], d = dst[e];
    float we = w[e];
    float dgo = deg_out[s]; dgo = (dgo > 0.f) ? dgo : 1.f;
    float dgi = deg_in[d];  dgi = (dgi > 0.f) ? dgi : 1.f;
    int pf = atomicAdd(&pos_f[d], 1);
    col_f[pf] = s; w_f[pf] = we / dgo;
    int pr = atomicAdd(&pos_r[s], 1);
    col_r[pr] = d; w_r[pr] = we / dgi;
}

// ---------------- converts ----------------
// W[l][d][k][f:128][o:64] fp32 -> Wt[l][g][d][k][o:64][f:128] bf16, with the
// (d0,k0)+(d1,k0) pair pre-summed into the (d0,k0) slot.
__global__ void convW_kernel(const float* __restrict__ Wz, const float* __restrict__ Wr,
                             const float* __restrict__ Wh, ushort* __restrict__ Wt) {
    int t = blockIdx.x * 256 + threadIdx.x;   // over 2*3*2*3*64*128 = 589824
    if (t >= 2 * 3 * 2 * 3 * 64 * 128) return;
    int f = t & 127;
    int r1 = t >> 7;
    int o = r1 & 63;
    int r2 = r1 >> 6;
    int k = r2 % 3;
    int r3 = r2 / 3;
    int d = r3 & 1;
    int r4 = r3 >> 1;
    int g = r4 % 3;
    int l = r4 / 3;
    const float* W = (g == 0) ? Wz : (g == 1) ? Wr : Wh;
    float v = W[(((long)(l * 2 + d) * 3 + k) * 128 + f) * 64 + o];
    if (k == 0 && d == 0)
        v += W[(((long)(l * 2 + 1) * 3 + 0) * 128 + f) * 64 + o];
    Wt[t] = f2b(v);
}

__global__ void convX_kernel(const float4* __restrict__ in, ushort4* __restrict__ out) {
    long t = (long)blockIdx.x * blockDim.x + threadIdx.x;   // over ROWS*16
    if (t >= (long)ROWS * 16) return;
    float4 v = in[t];
    ushort4 r;
    r.x = f2b(v.x); r.y = f2b(v.y); r.z = f2b(v.z); r.w = f2b(v.w);
    out[t] = r;
}

// ---------------- bf16 CSR gather prop: out = bf16(alpha*sum + beta*base) ----------------
__global__ __launch_bounds__(128) void gather_prop_b(
        const ushort* __restrict__ X, const ushort* __restrict__ base,
        const int* __restrict__ off, const int* __restrict__ col,
        const float* __restrict__ w, ushort* __restrict__ out,
        float alpha, float beta) {
    int n = blockIdx.x;
    int t = threadIdx.x;
    int b = t >> 4;          // 0..7
    int q = t & 15;          // feature quad (4 bf16 = 8B)
    int s = off[n], e = off[n + 1];
    float a0 = 0.f, a1 = 0.f, a2 = 0.f, a3 = 0.f;
    for (int j = s; j < e; ++j) {
        int c = col[j];
        float ww = w[j];
        ushort4 v = *(const ushort4*)&X[((long)b * NN + c) * 64 + q * 4];
        a0 = fmaf(b2f(v.x), ww, a0); a1 = fmaf(b2f(v.y), ww, a1);
        a2 = fmaf(b2f(v.z), ww, a2); a3 = fmaf(b2f(v.w), ww, a3);
    }
    long o = ((long)b * NN + n) * 64 + q * 4;
    a0 *= alpha; a1 *= alpha; a2 *= alpha; a3 *= alpha;
    if (beta != 0.f) {
        ushort4 bb = *(const ushort4*)&base[o];
        a0 = fmaf(beta, b2f(bb.x), a0); a1 = fmaf(beta, b2f(bb.y), a1);
        a2 = fmaf(beta, b2f(bb.z), a2); a3 = fmaf(beta, b2f(bb.w), a3);
    }
    ushort4 r;
    r.x = f2b(a0); r.y = f2b(a1); r.z = f2b(a2); r.w = f2b(a3);
    *(ushort4*)&out[o] = r;
}

// ---------------- MFMA 10-term GEMMs (no LDS, frags straight from global) ----------------
// A-frag: lane holds X[row0 + (lane&15)][ks*32 + (lane>>4)*8 + j]  (16B contiguous)
// B-frag: lane holds Wt[col0 + (lane&15)][ks*32 + (lane>>4)*8 + j] (Wt transposed, stride 128)
// C/D:    row = (lane>>4)*4 + q, col = lane&15   [verified m89 mapping]
struct GM10 {
    const ushort* X[10];
    const ushort* Wa[10];
    const ushort* Wb[10];
};

// dual gate: 4 waves; wid&1 = row half (64 rows), wid>>1 = gate (0:Z, 1:R)
__global__ __launch_bounds__(256) void mfma_dual(GM10 A, int nt,
        const float* __restrict__ bzp, const float* __restrict__ brp,
        const float* __restrict__ h,
        float* __restrict__ Z, ushort* __restrict__ rhb) {
    int lane = threadIdx.x & 63;
    int wid  = threadIdx.x >> 6;
    int gate = wid >> 1;
    long grow = (long)blockIdx.x * 128 + (long)(wid & 1) * 64;
    int lr = lane & 15;
    int lk = lane >> 4;
    f32x4 acc[4][4];
    #pragma unroll
    for (int i = 0; i < 4; ++i)
        #pragma unroll
        for (int j = 0; j < 4; ++j)
            acc[i][j] = (f32x4){0.f, 0.f, 0.f, 0.f};

    for (int tt = 0; tt < nt; ++tt) {
        const ushort* Xp = A.X[tt];
        const ushort* Wp = gate ? A.Wb[tt] : A.Wa[tt];
        bf16x8 a[2][4], b[2][4];
        #pragma unroll
        for (int ks = 0; ks < 2; ++ks)
            #pragma unroll
            for (int mi = 0; mi < 4; ++mi)
                a[ks][mi] = *(const bf16x8*)&Xp[(grow + mi * 16 + lr) * 64 + ks * 32 + lk * 8];
        #pragma unroll
        for (int ks = 0; ks < 2; ++ks)
            #pragma unroll
            for (int ni = 0; ni < 4; ++ni)
                b[ks][ni] = *(const bf16x8*)&Wp[(ni * 16 + lr) * 128 + ks * 32 + lk * 8];
        #pragma unroll
        for (int ks = 0; ks < 2; ++ks)
            #pragma unroll
            for (int mi = 0; mi < 4; ++mi)
                #pragma unroll
                for (int ni = 0; ni < 4; ++ni)
                    acc[mi][ni] = __builtin_amdgcn_mfma_f32_16x16x32_bf16(
                        a[ks][mi], b[ks][ni], acc[mi][ni], 0, 0, 0);
    }
    const float* bias = gate ? brp : bzp;
    #pragma unroll
    for (int mi = 0; mi < 4; ++mi) {
        #pragma unroll
        for (int q = 0; q < 4; ++q) {
            long row = grow + mi * 16 + lk * 4 + q;
            #pragma unroll
            for (int ni = 0; ni < 4; ++ni) {
                int colc = ni * 16 + lr;
                long idx = row * 64 + colc;
                float v = acc[mi][ni][q] + bias[colc];
                float sg = 1.f / (1.f + expf(-v));
                if (gate == 0) Z[idx] = sg;
                else           rhb[idx] = f2b(sg * h[idx]);
            }
        }
    }
}

// single gate (H): 2 waves; wid = row half; fused GRU blend epilogue
__global__ __launch_bounds__(128) void mfma_single(GM10 A, int nt,
        const float* __restrict__ bhp, const float* __restrict__ h,
        const float* __restrict__ Zg,
        float* __restrict__ outF, ushort* __restrict__ outB, int writeF) {
    int lane = threadIdx.x & 63;
    int wid  = threadIdx.x >> 6;
    long grow = (long)blockIdx.x * 128 + (long)wid * 64;
    int lr = lane & 15;
    int lk = lane >> 4;
    f32x4 acc[4][4];
    #pragma unroll
    for (int i = 0; i < 4; ++i)
        #pragma unroll
        for (int j = 0; j < 4; ++j)
            acc[i][j] = (f32x4){0.f, 0.f, 0.f, 0.f};

    for (int tt = 0; tt < nt; ++tt) {
        const ushort* Xp = A.X[tt];
        const ushort* Wp = A.Wa[tt];
        bf16x8 a[2][4], b[2][4];
        #pragma unroll
        for (int ks = 0; ks < 2; ++ks)
            #pragma unroll
            for (int mi = 0; mi < 4; ++mi)
                a[ks][mi] = *(const bf16x8*)&Xp[(grow + mi * 16 + lr) * 64 + ks * 32 + lk * 8];
        #pragma unroll
        for (int ks = 0; ks < 2; ++ks)
            #pragma unroll
            for (int ni = 0; ni < 4; ++ni)
                b[ks][ni] = *(const bf16x8*)&Wp[(ni * 16 + lr) * 128 + ks * 32 + lk * 8];
        #pragma unroll
        for (int ks = 0; ks < 2; ++ks)
            #pragma unroll
            for (int mi = 0; mi < 4; ++mi)
                #pragma unroll
                for (int ni = 0; ni < 4; ++ni)
                    acc[mi][ni] = __builtin_amdgcn_mfma_f32_16x16x32_bf16(
                        a[ks][mi], b[ks][ni], acc[mi][ni], 0, 0, 0);
    }
    #pragma unroll
    for (int mi = 0; mi < 4; ++mi) {
        #pragma unroll
        for (int q = 0; q < 4; ++q) {
            long row = grow + mi * 16 + lk * 4 + q;
            #pragma unroll
            for (int ni = 0; ni < 4; ++ni) {
                int colc = ni * 16 + lr;
                long idx = row * 64 + colc;
                float v = acc[mi][ni][q] + bhp[colc];
                float ht = tanhf(v);
                float z = Zg[idx];
                float res = z * h[idx] + (1.f - z) * ht;
                if (writeF) outF[idx] = res;
                else        outB[idx] = f2b(res);
            }
        }
    }
}

// ---------------- final projection 64 -> 32 ----------------
__global__ void proj_kernel(const float* __restrict__ last, const float* __restrict__ W,
                            const float* __restrict__ bias, float* __restrict__ out) {
    long t = (long)blockIdx.x * blockDim.x + threadIdx.x;
    if (t >= (long)ROWS * OUTD) return;
    long row = t >> 5;
    int  o   = (int)(t & 31);
    float acc = bias[o];
    #pragma unroll
    for (int hh = 0; hh < HIDD; ++hh)
        acc = fmaf(last[row * HIDD + hh], W[hh * OUTD + o], acc);
    out[t] = acc;
}

extern "C" void kernel_launch(void* const* d_in, const int* in_sizes, int n_in,
                              void* d_out, int out_size, void* d_ws, size_t ws_size,
                              hipStream_t stream) {
    const float* edge_weight = (const float*)d_in[0];
    const float* hidden      = (const float*)d_in[1];
    const float* go_input    = (const float*)d_in[2];
    const float* Wz = (const float*)d_in[3];
    const float* bz = (const float*)d_in[4];
    const float* Wr = (const float*)d_in[5];
    const float* br = (const float*)d_in[6];
    const float* Wh = (const float*)d_in[7];
    const float* bh = (const float*)d_in[8];
    const float* projW = (const float*)d_in[9];
    const float* projb = (const float*)d_in[10];
    const int*   eidx  = (const int*)d_in[11];
    const int* src = eidx;
    const int* dst = eidx + NE;
    float* out = (float*)d_out;

    // ---- workspace layout ----
    char* p = (char*)d_ws;
    auto alloc = [&](size_t bytes) { char* r = p; p += (bytes + 15) & ~(size_t)15; return r; };
    float* deg_out = (float*)alloc(NN * 4);        // first 4 arrays contiguous (zeroed together)
    float* deg_in  = (float*)alloc(NN * 4);
    int*   cnt_f   = (int*)alloc(NN * 4);
    int*   cnt_r   = (int*)alloc(NN * 4);
    int*   off_f   = (int*)alloc((NN + 4) * 4);
    int*   off_r   = (int*)alloc((NN + 4) * 4);
    int*   pos_f   = (int*)alloc(NN * 4);
    int*   pos_r   = (int*)alloc(NN * 4);
    int*   col_f   = (int*)alloc(NE * 4);
    float* w_f     = (float*)alloc(NE * 4);
    int*   col_r   = (int*)alloc(NE * 4);
    float* w_r     = (float*)alloc(NE * 4);
    ushort* Wt     = (ushort*)alloc((size_t)2 * 3 * 2 * 3 * 64 * 128 * 2);
    const size_t BB = (size_t)ROWS * HIDD * 2;     // 10.24 MB bf16 buffer
    ushort* curb  = (ushort*)alloc(BB);
    ushort* hb    = (ushort*)alloc(BB);
    ushort* rhb   = (ushort*)alloc(BB);
    ushort* cur1b = (ushort*)alloc(BB);
    ushort* T1f0  = (ushort*)alloc(BB);
    ushort* T2f0  = (ushort*)alloc(BB);
    ushort* T1r0  = (ushort*)alloc(BB);
    ushort* T2r0  = (ushort*)alloc(BB);
    ushort* T1f1  = (ushort*)alloc(BB);
    ushort* T2f1  = (ushort*)alloc(BB);
    ushort* T1r1  = (ushort*)alloc(BB);
    ushort* T2r1  = (ushort*)alloc(BB);
    float*  Zbuf  = (float*)alloc((size_t)ROWS * HIDD * 4);
    if ((size_t)(p - (char*)d_ws) > ws_size) return;

    const int TB = 256;
    const int EGRID = (NE + TB - 1) / TB;

    // ---- CSR build ----
    zero_kernel<<<(4 * NN + TB - 1) / TB, TB, 0, stream>>>((int*)deg_out, 4 * NN);
    deg_cnt_kernel<<<EGRID, TB, 0, stream>>>(edge_weight, src, dst, deg_out, deg_in, cnt_f, cnt_r);
    scan_kernel<<<1, 256, 0, stream>>>(cnt_f, off_f);
    scan_kernel<<<1, 256, 0, stream>>>(cnt_r, off_r);
    copy_pos_kernel<<<(NN + TB - 1) / TB, TB, 0, stream>>>(off_f, off_r, pos_f, pos_r);
    fill_kernel<<<EGRID, TB, 0, stream>>>(edge_weight, src, dst, deg_out, deg_in,
                                          pos_f, pos_r, col_f, w_f, col_r, w_r);

    // ---- weight convert (bf16, transposed, k0-pair folded) ----
    convW_kernel<<<2304, 256, 0, stream>>>(Wz, Wr, Wh, Wt);
    // cur = go_input -> bf16
    convX_kernel<<<5000, 256, 0, stream>>>((const float4*)go_input, (ushort4*)curb);

    auto wt_term = [&](int l, int g, int d, int k, int c) -> const ushort* {
        return Wt + ((((long)((l * 3 + g) * 2 + d) * 3 + k) * 64) * 128) + (long)c * 64;
    };
    auto prop = [&](const ushort* X, const ushort* base, const int* off, const int* col,
                    const float* w, ushort* o, float alpha, float beta) {
        gather_prop_b<<<NN, 128, 0, stream>>>(X, base, off, col, w, o, alpha, beta);
    };

    const int dd[5]  = {0, 0, 0, 1, 1};
    const int kk2[5] = {0, 1, 2, 1, 2};

    const ushort* curb_p = curb;
    for (int l = 0; l < NL; ++l) {
        const float* h = hidden + (long)l * ROWS * HIDD;
        convX_kernel<<<5000, 256, 0, stream>>>((const float4*)h, (ushort4*)hb);

        // chunk-0 diffusion of cur (shared by Z, R, H)
        prop(curb_p, nullptr, off_f, col_f, w_f, T1f0, 1.f, 0.f);
        prop(T1f0,  curb_p,  off_f, col_f, w_f, T2f0, 2.f, -1.f);
        prop(curb_p, nullptr, off_r, col_r, w_r, T1r0, 1.f, 0.f);
        prop(T1r0,  curb_p,  off_r, col_r, w_r, T2r0, 2.f, -1.f);
        // chunk-1 diffusion of h (for Z/R)
        prop(hb, nullptr, off_f, col_f, w_f, T1f1, 1.f, 0.f);
        prop(T1f1, hb,    off_f, col_f, w_f, T2f1, 2.f, -1.f);
        prop(hb, nullptr, off_r, col_r, w_r, T1r1, 1.f, 0.f);
        prop(T1r1, hb,    off_r, col_r, w_r, T2r1, 2.f, -1.f);

        const ushort* xs0[5] = {curb_p, T1f0, T2f0, T1r0, T2r0};
        const ushort* xs1[5] = {hb,     T1f1, T2f1, T1r1, T2r1};
        GM10 A{};
        for (int i = 0; i < 5; ++i) {
            A.X[i] = xs0[i];
            A.Wa[i] = wt_term(l, 0, dd[i], kk2[i], 0);
            A.Wb[i] = wt_term(l, 1, dd[i], kk2[i], 0);
            A.X[5 + i] = xs1[i];
            A.Wa[5 + i] = wt_term(l, 0, dd[i], kk2[i], 1);
            A.Wb[5 + i] = wt_term(l, 1, dd[i], kk2[i], 1);
        }
        mfma_dual<<<ROWS / 128, 256, 0, stream>>>(A, 10, bz + l * HIDD, br + l * HIDD,
                                                  h, Zbuf, rhb);

        // chunk-1 diffusion of rh (for H)
        prop(rhb, nullptr, off_f, col_f, w_f, T1f1, 1.f, 0.f);
        prop(T1f1, rhb,   off_f, col_f, w_f, T2f1, 2.f, -1.f);
        prop(rhb, nullptr, off_r, col_r, w_r, T1r1, 1.f, 0.f);
        prop(T1r1, rhb,   off_r, col_r, w_r, T2r1, 2.f, -1.f);

        GM10 Ah{};
        const ushort* xh1[5] = {rhb, T1f1, T2f1, T1r1, T2r1};
        for (int i = 0; i < 5; ++i) {
            Ah.X[i] = xs0[i];
            Ah.Wa[i] = wt_term(l, 2, dd[i], kk2[i], 0);
            Ah.X[5 + i] = xh1[i];
            Ah.Wa[5 + i] = wt_term(l, 2, dd[i], kk2[i], 1);
        }
        mfma_single<<<ROWS / 128, 128, 0, stream>>>(Ah, 10, bh + l * HIDD, h, Zbuf,
                                                    Zbuf, cur1b, (l == NL - 1) ? 1 : 0);
        curb_p = cur1b;
    }

    proj_kernel<<<(int)(((long)ROWS * OUTD + TB - 1) / TB), TB, 0, stream>>>(
        Zbuf, projW, projb, out);
}

// Round 5
// 1295.428 us; speedup vs baseline: 5.2095x; 1.0633x over previous
//
#include <hip/hip_runtime.h>
#include <math.h>

#define NL 2
#define KK 3
#define HIDD 64
#define OUTD 32
#define NB 8
#define NN 10000
#define NE 160000
#define ROWS 80000            // NB*NN
#define WSTRIDE (128*HIDD)    // 8192 floats per W[l,d,k]

typedef __attribute__((ext_vector_type(8))) short bf16x8;
typedef __attribute__((ext_vector_type(4))) float f32x4;

__device__ __forceinline__ ushort f2b(float x) {
    union { float f; unsigned u; } v; v.f = x;
    unsigned r = (v.u + 0x7fff + ((v.u >> 16) & 1)) >> 16;
    return (ushort)r;
}
__device__ __forceinline__ float b2f(ushort u) {
    union { unsigned u; float f; } v; v.u = (unsigned)u << 16;
    return v.f;
}

// ---------------- setup: zero small arrays ----------------
__global__ void zero_kernel(int* p, long n) {
    long t = (long)blockIdx.x * blockDim.x + threadIdx.x;
    if (t < n) p[t] = 0;
}

// ---------------- degree + CSR counts ----------------
__global__ void deg_cnt_kernel(const float* __restrict__ w, const int* __restrict__ src,
                               const int* __restrict__ dst, float* deg_out, float* deg_in,
                               int* cnt_f, int* cnt_r) {
    int e = blockIdx.x * blockDim.x + threadIdx.x;
    if (e >= NE) return;
    int s = src[e], d = dst[e];
    float we = w[e];
    atomicAdd(&deg_out[s], we);
    atomicAdd(&deg_in[d], we);
    atomicAdd(&cnt_f[d], 1);
    atomicAdd(&cnt_r[s], 1);
}

__global__ void scan_kernel(const int* __restrict__ cnt, int* __restrict__ off) {
    __shared__ int part[256];
    const int CH = (NN + 255) / 256;
    int t = threadIdx.x;
    int s = 0;
    for (int i = 0; i < CH; ++i) {
        int idx = t * CH + i;
        if (idx < NN) s += cnt[idx];
    }
    part[t] = s;
    __syncthreads();
    if (t == 0) {
        int run = 0;
        for (int i = 0; i < 256; ++i) { int v = part[i]; part[i] = run; run += v; }
        off[NN] = run;
    }
    __syncthreads();
    int run = part[t];
    for (int i = 0; i < CH; ++i) {
        int idx = t * CH + i;
        if (idx < NN) { off[idx] = run; run += cnt[idx]; }
    }
}

__global__ void copy_pos_kernel(const int* __restrict__ off_f, const int* __restrict__ off_r,
                                int* pos_f, int* pos_r) {
    int t = blockIdx.x * blockDim.x + threadIdx.x;
    if (t < NN) { pos_f[t] = off_f[t]; pos_r[t] = off_r[t]; }
}

__global__ void fill_kernel(const float* __restrict__ w, const int* __restrict__ src,
                            const int* __restrict__ dst, const float* __restrict__ deg_out,
                            const float* __restrict__ deg_in,
                            int* pos_f, int* pos_r,
                            int* col_f, float* w_f, int* col_r, float* w_r) {
    int e = blockIdx.x * blockDim.x + threadIdx.x;
    if (e >= NE) return;
    int s = src[e], d = dst[e];
    float we = w[e];
    float dgo = deg_out[s]; dgo = (dgo > 0.f) ? dgo : 1.f;
    float dgi = deg_in[d];  dgi = (dgi > 0.f) ? dgi : 1.f;
    int pf = atomicAdd(&pos_f[d], 1);
    col_f[pf] = s; w_f[pf] = we / dgo;
    int pr = atomicAdd(&pos_r[s], 1);
    col_r[pr] = d; w_r[pr] = we / dgi;
}

// ---------------- converts ----------------
__global__ void convW_kernel(const float* __restrict__ Wz, const float* __restrict__ Wr,
                             const float* __restrict__ Wh, ushort* __restrict__ Wt) {
    int t = blockIdx.x * 256 + threadIdx.x;   // over 2*3*2*3*64*128 = 589824
    if (t >= 2 * 3 * 2 * 3 * 64 * 128) return;
    int f = t & 127;
    int r1 = t >> 7;
    int o = r1 & 63;
    int r2 = r1 >> 6;
    int k = r2 % 3;
    int r3 = r2 / 3;
    int d = r3 & 1;
    int r4 = r3 >> 1;
    int g = r4 % 3;
    int l = r4 / 3;
    const float* W = (g == 0) ? Wz : (g == 1) ? Wr : Wh;
    float v = W[(((long)(l * 2 + d) * 3 + k) * 128 + f) * 64 + o];
    if (k == 0 && d == 0)
        v += W[(((long)(l * 2 + 1) * 3 + 0) * 128 + f) * 64 + o];
    Wt[t] = f2b(v);
}

__global__ void convX_kernel(const float4* __restrict__ in, ushort4* __restrict__ out) {
    long t = (long)blockIdx.x * blockDim.x + threadIdx.x;   // over ROWS*16
    if (t >= (long)ROWS * 16) return;
    float4 v = in[t];
    ushort4 r;
    r.x = f2b(v.x); r.y = f2b(v.y); r.z = f2b(v.z); r.w = f2b(v.w);
    out[t] = r;
}

// ---------------- bf16 CSR gather prop: out = bf16(alpha*sum + beta*base) ----------------
__global__ __launch_bounds__(128) void gather_prop_b(
        const ushort* __restrict__ X, const ushort* __restrict__ base,
        const int* __restrict__ off, const int* __restrict__ col,
        const float* __restrict__ w, ushort* __restrict__ out,
        float alpha, float beta) {
    int n = blockIdx.x;
    int t = threadIdx.x;
    int b = t >> 4;          // 0..7
    int q = t & 15;          // feature quad (4 bf16 = 8B)
    int s = off[n], e = off[n + 1];
    float a0 = 0.f, a1 = 0.f, a2 = 0.f, a3 = 0.f;
    int j = s;
    for (; j + 2 <= e; j += 2) {
        int c0 = col[j], c1 = col[j + 1];
        float w0 = w[j], w1 = w[j + 1];
        ushort4 v0 = *(const ushort4*)&X[((long)b * NN + c0) * 64 + q * 4];
        ushort4 v1 = *(const ushort4*)&X[((long)b * NN + c1) * 64 + q * 4];
        a0 = fmaf(b2f(v0.x), w0, a0); a1 = fmaf(b2f(v0.y), w0, a1);
        a2 = fmaf(b2f(v0.z), w0, a2); a3 = fmaf(b2f(v0.w), w0, a3);
        a0 = fmaf(b2f(v1.x), w1, a0); a1 = fmaf(b2f(v1.y), w1, a1);
        a2 = fmaf(b2f(v1.z), w1, a2); a3 = fmaf(b2f(v1.w), w1, a3);
    }
    if (j < e) {
        int c = col[j];
        float ww = w[j];
        ushort4 v = *(const ushort4*)&X[((long)b * NN + c) * 64 + q * 4];
        a0 = fmaf(b2f(v.x), ww, a0); a1 = fmaf(b2f(v.y), ww, a1);
        a2 = fmaf(b2f(v.z), ww, a2); a3 = fmaf(b2f(v.w), ww, a3);
    }
    long o = ((long)b * NN + n) * 64 + q * 4;
    a0 *= alpha; a1 *= alpha; a2 *= alpha; a3 *= alpha;
    if (beta != 0.f) {
        ushort4 bb = *(const ushort4*)&base[o];
        a0 = fmaf(beta, b2f(bb.x), a0); a1 = fmaf(beta, b2f(bb.y), a1);
        a2 = fmaf(beta, b2f(bb.z), a2); a3 = fmaf(beta, b2f(bb.w), a3);
    }
    ushort4 r;
    r.x = f2b(a0); r.y = f2b(a1); r.z = f2b(a2); r.w = f2b(a3);
    *(ushort4*)&out[o] = r;
}

// ---------------- MFMA 10-term GEMMs, register-pipelined ----------------
// A-frag: lane holds X[row0 + (lane&15)][ks*32 + (lane>>4)*8 + j]
// B-frag: lane holds Wt[col0 + (lane&15)][ks*32 + (lane>>4)*8 + j] (Wt transposed)
// C/D:    row = (lane>>4)*4 + q, col = lane&15
struct GM10 {
    const ushort* X[10];
    const ushort* Wa[10];
    const ushort* Wb[10];
};

#define LOADF(tt, aa, bb)                                                          \
    {                                                                              \
        const ushort* Xp = A.X[tt];                                                \
        const ushort* Wp = gate ? A.Wb[tt] : A.Wa[tt];                             \
        _Pragma("unroll")                                                          \
        for (int ks = 0; ks < 2; ++ks) {                                           \
            _Pragma("unroll")                                                      \
            for (int mi = 0; mi < 2; ++mi)                                         \
                aa[ks][mi] = *(const bf16x8*)&Xp[(grow + mi * 16 + lr) * 64 +      \
                                                 ks * 32 + lk * 8];                \
            _Pragma("unroll")                                                      \
            for (int ni = 0; ni < 4; ++ni)                                         \
                bb[ks][ni] = *(const bf16x8*)&Wp[(ni * 16 + lr) * 128 +            \
                                                 ks * 32 + lk * 8];                \
        }                                                                          \
    }

#define MFMAF(aa, bb)                                                              \
    _Pragma("unroll")                                                              \
    for (int ks = 0; ks < 2; ++ks)                                                 \
        _Pragma("unroll")                                                          \
        for (int mi = 0; mi < 2; ++mi)                                             \
            _Pragma("unroll")                                                      \
            for (int ni = 0; ni < 4; ++ni)                                         \
                acc[mi][ni] = __builtin_amdgcn_mfma_f32_16x16x32_bf16(             \
                    aa[ks][mi], bb[ks][ni], acc[mi][ni], 0, 0, 0);

// dual gate: 64 rows/block, 4 waves (gate x 32-row half)
template<int NT>
__global__ __launch_bounds__(256) void mfma_dual(GM10 A,
        const float* __restrict__ bzp, const float* __restrict__ brp,
        const float* __restrict__ h,
        float* __restrict__ Z, ushort* __restrict__ rhb) {
    int lane = threadIdx.x & 63;
    int wid  = threadIdx.x >> 6;
    int gate = wid >> 1;
    long grow = (long)blockIdx.x * 64 + (long)(wid & 1) * 32;
    int lr = lane & 15;
    int lk = lane >> 4;
    f32x4 acc[2][4];
    #pragma unroll
    for (int i = 0; i < 2; ++i)
        #pragma unroll
        for (int j = 0; j < 4; ++j)
            acc[i][j] = (f32x4){0.f, 0.f, 0.f, 0.f};

    bf16x8 a0[2][2], b0[2][4], a1[2][2], b1[2][4];
    LOADF(0, a0, b0);
    #pragma unroll
    for (int tt = 0; tt < NT; tt += 2) {
        if (tt + 1 < NT) LOADF(tt + 1, a1, b1);
        MFMAF(a0, b0);
        if (tt + 2 < NT) LOADF(tt + 2, a0, b0);
        if (tt + 1 < NT) MFMAF(a1, b1);
    }

    const float* bias = gate ? brp : bzp;
    #pragma unroll
    for (int mi = 0; mi < 2; ++mi) {
        #pragma unroll
        for (int q = 0; q < 4; ++q) {
            long row = grow + mi * 16 + lk * 4 + q;
            #pragma unroll
            for (int ni = 0; ni < 4; ++ni) {
                int colc = ni * 16 + lr;
                long idx = row * 64 + colc;
                float v = acc[mi][ni][q] + bias[colc];
                float sg = 1.f / (1.f + expf(-v));
                if (gate == 0) Z[idx] = sg;
                else           rhb[idx] = f2b(sg * h[idx]);
            }
        }
    }
}

// single gate (H): 64 rows/block, 2 waves; fused GRU blend epilogue
template<int NT>
__global__ __launch_bounds__(128) void mfma_single(GM10 A,
        const float* __restrict__ bhp, const float* __restrict__ h,
        const float* __restrict__ Zg,
        float* __restrict__ outF, ushort* __restrict__ outB, int writeF) {
    int lane = threadIdx.x & 63;
    int wid  = threadIdx.x >> 6;
    const int gate = 0;   // use Wa
    long grow = (long)blockIdx.x * 64 + (long)wid * 32;
    int lr = lane & 15;
    int lk = lane >> 4;
    f32x4 acc[2][4];
    #pragma unroll
    for (int i = 0; i < 2; ++i)
        #pragma unroll
        for (int j = 0; j < 4; ++j)
            acc[i][j] = (f32x4){0.f, 0.f, 0.f, 0.f};

    bf16x8 a0[2][2], b0[2][4], a1[2][2], b1[2][4];
    LOADF(0, a0, b0);
    #pragma unroll
    for (int tt = 0; tt < NT; tt += 2) {
        if (tt + 1 < NT) LOADF(tt + 1, a1, b1);
        MFMAF(a0, b0);
        if (tt + 2 < NT) LOADF(tt + 2, a0, b0);
        if (tt + 1 < NT) MFMAF(a1, b1);
    }

    #pragma unroll
    for (int mi = 0; mi < 2; ++mi) {
        #pragma unroll
        for (int q = 0; q < 4; ++q) {
            long row = grow + mi * 16 + lk * 4 + q;
            #pragma unroll
            for (int ni = 0; ni < 4; ++ni) {
                int colc = ni * 16 + lr;
                long idx = row * 64 + colc;
                float v = acc[mi][ni][q] + bhp[colc];
                float ht = tanhf(v);
                float z = Zg[idx];
                float res = z * h[idx] + (1.f - z) * ht;
                if (writeF) outF[idx] = res;
                else        outB[idx] = f2b(res);
            }
        }
    }
}

// ---------------- final projection 64 -> 32 ----------------
__global__ void proj_kernel(const float* __restrict__ last, const float* __restrict__ W,
                            const float* __restrict__ bias, float* __restrict__ out) {
    long t = (long)blockIdx.x * blockDim.x + threadIdx.x;
    if (t >= (long)ROWS * OUTD) return;
    long row = t >> 5;
    int  o   = (int)(t & 31);
    float acc = bias[o];
    #pragma unroll
    for (int hh = 0; hh < HIDD; ++hh)
        acc = fmaf(last[row * HIDD + hh], W[hh * OUTD + o], acc);
    out[t] = acc;
}

extern "C" void kernel_launch(void* const* d_in, const int* in_sizes, int n_in,
                              void* d_out, int out_size, void* d_ws, size_t ws_size,
                              hipStream_t stream) {
    const float* edge_weight = (const float*)d_in[0];
    const float* hidden      = (const float*)d_in[1];
    const float* go_input    = (const float*)d_in[2];
    const float* Wz = (const float*)d_in[3];
    const float* bz = (const float*)d_in[4];
    const float* Wr = (const float*)d_in[5];
    const float* br = (const float*)d_in[6];
    const float* Wh = (const float*)d_in[7];
    const float* bh = (const float*)d_in[8];
    const float* projW = (const float*)d_in[9];
    const float* projb = (const float*)d_in[10];
    const int*   eidx  = (const int*)d_in[11];
    const int* src = eidx;
    const int* dst = eidx + NE;
    float* out = (float*)d_out;

    // ---- workspace layout ----
    char* p = (char*)d_ws;
    auto alloc = [&](size_t bytes) { char* r = p; p += (bytes + 15) & ~(size_t)15; return r; };
    float* deg_out = (float*)alloc(NN * 4);
    float* deg_in  = (float*)alloc(NN * 4);
    int*   cnt_f   = (int*)alloc(NN * 4);
    int*   cnt_r   = (int*)alloc(NN * 4);
    int*   off_f   = (int*)alloc((NN + 4) * 4);
    int*   off_r   = (int*)alloc((NN + 4) * 4);
    int*   pos_f   = (int*)alloc(NN * 4);
    int*   pos_r   = (int*)alloc(NN * 4);
    int*   col_f   = (int*)alloc(NE * 4);
    float* w_f     = (float*)alloc(NE * 4);
    int*   col_r   = (int*)alloc(NE * 4);
    float* w_r     = (float*)alloc(NE * 4);
    ushort* Wt     = (ushort*)alloc((size_t)2 * 3 * 2 * 3 * 64 * 128 * 2);
    const size_t BB = (size_t)ROWS * HIDD * 2;     // 10.24 MB bf16 buffer
    ushort* curb  = (ushort*)alloc(BB);
    ushort* hb    = (ushort*)alloc(BB);
    ushort* rhb   = (ushort*)alloc(BB);
    ushort* cur1b = (ushort*)alloc(BB);
    ushort* T1f0  = (ushort*)alloc(BB);
    ushort* T2f0  = (ushort*)alloc(BB);
    ushort* T1r0  = (ushort*)alloc(BB);
    ushort* T2r0  = (ushort*)alloc(BB);
    ushort* T1f1  = (ushort*)alloc(BB);
    ushort* T2f1  = (ushort*)alloc(BB);
    ushort* T1r1  = (ushort*)alloc(BB);
    ushort* T2r1  = (ushort*)alloc(BB);
    float*  Zbuf  = (float*)alloc((size_t)ROWS * HIDD * 4);
    if ((size_t)(p - (char*)d_ws) > ws_size) return;

    const int TB = 256;
    const int EGRID = (NE + TB - 1) / TB;

    // ---- CSR build ----
    zero_kernel<<<(4 * NN + TB - 1) / TB, TB, 0, stream>>>((int*)deg_out, 4 * NN);
    deg_cnt_kernel<<<EGRID, TB, 0, stream>>>(edge_weight, src, dst, deg_out, deg_in, cnt_f, cnt_r);
    scan_kernel<<<1, 256, 0, stream>>>(cnt_f, off_f);
    scan_kernel<<<1, 256, 0, stream>>>(cnt_r, off_r);
    copy_pos_kernel<<<(NN + TB - 1) / TB, TB, 0, stream>>>(off_f, off_r, pos_f, pos_r);
    fill_kernel<<<EGRID, TB, 0, stream>>>(edge_weight, src, dst, deg_out, deg_in,
                                          pos_f, pos_r, col_f, w_f, col_r, w_r);

    // ---- weight convert (bf16, transposed, k0-pair folded) ----
    convW_kernel<<<2304, 256, 0, stream>>>(Wz, Wr, Wh, Wt);
    convX_kernel<<<5000, 256, 0, stream>>>((const float4*)go_input, (ushort4*)curb);

    auto wt_term = [&](int l, int g, int d, int k, int c) -> const ushort* {
        return Wt + ((((long)((l * 3 + g) * 2 + d) * 3 + k) * 64) * 128) + (long)c * 64;
    };
    auto prop = [&](const ushort* X, const ushort* base, const int* off, const int* col,
                    const float* w, ushort* o, float alpha, float beta) {
        gather_prop_b<<<NN, 128, 0, stream>>>(X, base, off, col, w, o, alpha, beta);
    };

    const int dd[5]  = {0, 0, 0, 1, 1};
    const int kk2[5] = {0, 1, 2, 1, 2};

    const ushort* curb_p = curb;
    for (int l = 0; l < NL; ++l) {
        const float* h = hidden + (long)l * ROWS * HIDD;
        convX_kernel<<<5000, 256, 0, stream>>>((const float4*)h, (ushort4*)hb);

        // chunk-0 diffusion of cur (shared by Z, R, H)
        prop(curb_p, nullptr, off_f, col_f, w_f, T1f0, 1.f, 0.f);
        prop(T1f0,  curb_p,  off_f, col_f, w_f, T2f0, 2.f, -1.f);
        prop(curb_p, nullptr, off_r, col_r, w_r, T1r0, 1.f, 0.f);
        prop(T1r0,  curb_p,  off_r, col_r, w_r, T2r0, 2.f, -1.f);
        // chunk-1 diffusion of h (for Z/R)
        prop(hb, nullptr, off_f, col_f, w_f, T1f1, 1.f, 0.f);
        prop(T1f1, hb,    off_f, col_f, w_f, T2f1, 2.f, -1.f);
        prop(hb, nullptr, off_r, col_r, w_r, T1r1, 1.f, 0.f);
        prop(T1r1, hb,    off_r, col_r, w_r, T2r1, 2.f, -1.f);

        const ushort* xs0[5] = {curb_p, T1f0, T2f0, T1r0, T2r0};
        const ushort* xs1[5] = {hb,     T1f1, T2f1, T1r1, T2r1};
        GM10 A{};
        for (int i = 0; i < 5; ++i) {
            A.X[i] = xs0[i];
            A.Wa[i] = wt_term(l, 0, dd[i], kk2[i], 0);
            A.Wb[i] = wt_term(l, 1, dd[i], kk2[i], 0);
            A.X[5 + i] = xs1[i];
            A.Wa[5 + i] = wt_term(l, 0, dd[i], kk2[i], 1);
            A.Wb[5 + i] = wt_term(l, 1, dd[i], kk2[i], 1);
        }
        mfma_dual<10><<<ROWS / 64, 256, 0, stream>>>(A, bz + l * HIDD, br + l * HIDD,
                                                     h, Zbuf, rhb);

        // chunk-1 diffusion of rh (for H)
        prop(rhb, nullptr, off_f, col_f, w_f, T1f1, 1.f, 0.f);
        prop(T1f1, rhb,   off_f, col_f, w_f, T2f1, 2.f, -1.f);
        prop(rhb, nullptr, off_r, col_r, w_r, T1r1, 1.f, 0.f);
        prop(T1r1, rhb,   off_r, col_r, w_r, T2r1, 2.f, -1.f);

        GM10 Ah{};
        const ushort* xh1[5] = {rhb, T1f1, T2f1, T1r1, T2r1};
        for (int i = 0; i < 5; ++i) {
            Ah.X[i] = xs0[i];
            Ah.Wa[i] = wt_term(l, 2, dd[i], kk2[i], 0);
            Ah.X[5 + i] = xh1[i];
            Ah.Wa[5 + i] = wt_term(l, 2, dd[i], kk2[i], 1);
        }
        mfma_single<10><<<ROWS / 64, 128, 0, stream>>>(Ah, bh + l * HIDD, h, Zbuf,
                                                       Zbuf, cur1b, (l == NL - 1) ? 1 : 0);
        curb_p = cur1b;
    }

    proj_kernel<<<(int)(((long)ROWS * OUTD + TB - 1) / TB), TB, 0, stream>>>(
        Zbuf, projW, projb, out);
}

// Round 6
// 1175.430 us; speedup vs baseline: 5.7413x; 1.1021x over previous
//
#include <hip/hip_runtime.h>
#include <math.h>

#define NL 2
#define KK 3
#define HIDD 64
#define OUTD 32
#define NB 8
#define NN 10000
#define NE 160000
#define ROWS 80000            // NB*NN;  permuted row index = n*8 + b
#define WSTRIDE (128*HIDD)    // 8192 floats per W[l,d,k]

typedef __attribute__((ext_vector_type(8))) short bf16x8;
typedef __attribute__((ext_vector_type(8))) unsigned short u16x8;
typedef __attribute__((ext_vector_type(4))) float f32x4;

__device__ __forceinline__ ushort f2b(float x) {
    union { float f; unsigned u; } v; v.f = x;
    unsigned r = (v.u + 0x7fff + ((v.u >> 16) & 1)) >> 16;
    return (ushort)r;
}
__device__ __forceinline__ float b2f(ushort u) {
    union { unsigned u; float f; } v; v.u = (unsigned)u << 16;
    return v.f;
}

// ---------------- setup ----------------
__global__ void zero_kernel(int* p, long n) {
    long t = (long)blockIdx.x * blockDim.x + threadIdx.x;
    if (t < n) p[t] = 0;
}

__global__ void deg_cnt_kernel(const float* __restrict__ w, const int* __restrict__ src,
                               const int* __restrict__ dst, float* deg_out, float* deg_in,
                               int* cnt_f, int* cnt_r) {
    int e = blockIdx.x * blockDim.x + threadIdx.x;
    if (e >= NE) return;
    int s = src[e], d = dst[e];
    float we = w[e];
    atomicAdd(&deg_out[s], we);
    atomicAdd(&deg_in[d], we);
    atomicAdd(&cnt_f[d], 1);
    atomicAdd(&cnt_r[s], 1);
}

__global__ void scan_kernel(const int* __restrict__ cnt, int* __restrict__ off) {
    __shared__ int part[256];
    const int CH = (NN + 255) / 256;
    int t = threadIdx.x;
    int s = 0;
    for (int i = 0; i < CH; ++i) {
        int idx = t * CH + i;
        if (idx < NN) s += cnt[idx];
    }
    part[t] = s;
    __syncthreads();
    if (t == 0) {
        int run = 0;
        for (int i = 0; i < 256; ++i) { int v = part[i]; part[i] = run; run += v; }
        off[NN] = run;
    }
    __syncthreads();
    int run = part[t];
    for (int i = 0; i < CH; ++i) {
        int idx = t * CH + i;
        if (idx < NN) { off[idx] = run; run += cnt[idx]; }
    }
}

__global__ void copy_pos_kernel(const int* __restrict__ off_f, const int* __restrict__ off_r,
                                int* pos_f, int* pos_r) {
    int t = blockIdx.x * blockDim.x + threadIdx.x;
    if (t < NN) { pos_f[t] = off_f[t]; pos_r[t] = off_r[t]; }
}

__global__ void fill_kernel(const float* __restrict__ w, const int* __restrict__ src,
                            const int* __restrict__ dst, const float* __restrict__ deg_out,
                            const float* __restrict__ deg_in,
                            int* pos_f, int* pos_r,
                            int* col_f, float* w_f, int* col_r, float* w_r) {
    int e = blockIdx.x * blockDim.x + threadIdx.x;
    if (e >= NE) return;
    int s = src[e], d = dst[e];
    float we = w[e];
    float dgo = deg_out[s]; dgo = (dgo > 0.f) ? dgo : 1.f;
    float dgi = deg_in[d];  dgi = (dgi > 0.f) ? dgi : 1.f;
    int pf = atomicAdd(&pos_f[d], 1);
    col_f[pf] = s; w_f[pf] = we / dgo;
    int pr = atomicAdd(&pos_r[s], 1);
    col_r[pr] = d; w_r[pr] = we / dgi;
}

// ---------------- converts ----------------
// W[l][d][k][f:128][o:64] fp32 -> Wt[l][g][d][k][o:64][f:128] bf16 (k0 dir-pair folded)
__global__ void convW_kernel(const float* __restrict__ Wz, const float* __restrict__ Wr,
                             const float* __restrict__ Wh, ushort* __restrict__ Wt) {
    int t = blockIdx.x * 256 + threadIdx.x;   // over 589824
    if (t >= 2 * 3 * 2 * 3 * 64 * 128) return;
    int f = t & 127;
    int r1 = t >> 7;
    int o = r1 & 63;
    int r2 = r1 >> 6;
    int k = r2 % 3;
    int r3 = r2 / 3;
    int d = r3 & 1;
    int r4 = r3 >> 1;
    int g = r4 % 3;
    int l = r4 / 3;
    const float* W = (g == 0) ? Wz : (g == 1) ? Wr : Wh;
    float v = W[(((long)(l * 2 + d) * 3 + k) * 128 + f) * 64 + o];
    if (k == 0 && d == 0)
        v += W[(((long)(l * 2 + 1) * 3 + 0) * 128 + f) * 64 + o];
    Wt[t] = f2b(v);
}

// [B][N][64] fp32 -> xh[(n*8+b)*128 + c*64 ..] bf16
__global__ void convX_perm(const float4* __restrict__ in, ushort* __restrict__ xh, int c) {
    long t = (long)blockIdx.x * blockDim.x + threadIdx.x;   // over ROWS*16 float4s
    if (t >= (long)ROWS * 16) return;
    int q = (int)(t & 15);
    long rowin = t >> 4;            // b*NN + n
    int b = (int)(rowin / NN);
    int n = (int)(rowin - (long)b * NN);
    float4 v = in[t];
    ushort4 r;
    r.x = f2b(v.x); r.y = f2b(v.y); r.z = f2b(v.z); r.w = f2b(v.w);
    long orow = (long)n * 8 + b;
    *(ushort4*)&xh[orow * 128 + c * 64 + q * 4] = r;
}

// ---------------- coalesced CSR props (batch-inner layout) ----------------
// full row: 1024 ushorts ([B=8][128]); 128 threads x 16B
__global__ __launch_bounds__(128) void prop_full(
        const ushort* __restrict__ Xf, const ushort* __restrict__ Xr,
        const ushort* __restrict__ base,
        const int* __restrict__ off_f, const int* __restrict__ col_f,
        const float* __restrict__ w_f,
        const int* __restrict__ off_r, const int* __restrict__ col_r,
        const float* __restrict__ w_r,
        ushort* __restrict__ outf, ushort* __restrict__ outr,
        float alpha, float beta) {
    int n = blockIdx.x;
    const ushort* X; const int* off; const int* col; const float* w; ushort* out;
    if (blockIdx.y == 0) { X = Xf; off = off_f; col = col_f; w = w_f; out = outf; }
    else                 { X = Xr; off = off_r; col = col_r; w = w_r; out = outr; }
    int t = threadIdx.x;
    int s = off[n], e = off[n + 1];
    float acc[8];
    #pragma unroll
    for (int i = 0; i < 8; ++i) acc[i] = 0.f;
    int j = s;
    for (; j + 2 <= e; j += 2) {
        int c0 = col[j], c1 = col[j + 1];
        float w0 = w[j], w1 = w[j + 1];
        u16x8 v0 = *(const u16x8*)&X[(long)c0 * 1024 + t * 8];
        u16x8 v1 = *(const u16x8*)&X[(long)c1 * 1024 + t * 8];
        #pragma unroll
        for (int i = 0; i < 8; ++i) acc[i] = fmaf(b2f(v0[i]), w0, acc[i]);
        #pragma unroll
        for (int i = 0; i < 8; ++i) acc[i] = fmaf(b2f(v1[i]), w1, acc[i]);
    }
    if (j < e) {
        int c = col[j];
        float ww = w[j];
        u16x8 v = *(const u16x8*)&X[(long)c * 1024 + t * 8];
        #pragma unroll
        for (int i = 0; i < 8; ++i) acc[i] = fmaf(b2f(v[i]), ww, acc[i]);
    }
    long o = (long)n * 1024 + t * 8;
    #pragma unroll
    for (int i = 0; i < 8; ++i) acc[i] *= alpha;
    if (beta != 0.f) {
        u16x8 bb = *(const u16x8*)&base[o];
        #pragma unroll
        for (int i = 0; i < 8; ++i) acc[i] = fmaf(beta, b2f(bb[i]), acc[i]);
    }
    u16x8 r;
    #pragma unroll
    for (int i = 0; i < 8; ++i) r[i] = f2b(acc[i]);
    *(u16x8*)&out[o] = r;
}

// chunk-1 half (64 feats x 8 batches within the 128-stride rows); 64 threads x 16B
__global__ __launch_bounds__(64) void prop_half(
        const ushort* __restrict__ Xf, const ushort* __restrict__ Xr,
        const ushort* __restrict__ base,
        const int* __restrict__ off_f, const int* __restrict__ col_f,
        const float* __restrict__ w_f,
        const int* __restrict__ off_r, const int* __restrict__ col_r,
        const float* __restrict__ w_r,
        ushort* __restrict__ outf, ushort* __restrict__ outr,
        float alpha, float beta) {
    int n = blockIdx.x;
    const ushort* X; const int* off; const int* col; const float* w; ushort* out;
    if (blockIdx.y == 0) { X = Xf; off = off_f; col = col_f; w = w_f; out = outf; }
    else                 { X = Xr; off = off_r; col = col_r; w = w_r; out = outr; }
    int t = threadIdx.x;
    int elem = (t >> 3) * 128 + 64 + (t & 7) * 8;   // [b][64 + f8*8]
    int s = off[n], e = off[n + 1];
    float acc[8];
    #pragma unroll
    for (int i = 0; i < 8; ++i) acc[i] = 0.f;
    int j = s;
    for (; j + 2 <= e; j += 2) {
        int c0 = col[j], c1 = col[j + 1];
        float w0 = w[j], w1 = w[j + 1];
        u16x8 v0 = *(const u16x8*)&X[(long)c0 * 1024 + elem];
        u16x8 v1 = *(const u16x8*)&X[(long)c1 * 1024 + elem];
        #pragma unroll
        for (int i = 0; i < 8; ++i) acc[i] = fmaf(b2f(v0[i]), w0, acc[i]);
        #pragma unroll
        for (int i = 0; i < 8; ++i) acc[i] = fmaf(b2f(v1[i]), w1, acc[i]);
    }
    if (j < e) {
        int c = col[j];
        float ww = w[j];
        u16x8 v = *(const u16x8*)&X[(long)c * 1024 + elem];
        #pragma unroll
        for (int i = 0; i < 8; ++i) acc[i] = fmaf(b2f(v[i]), ww, acc[i]);
    }
    long o = (long)n * 1024 + elem;
    #pragma unroll
    for (int i = 0; i < 8; ++i) acc[i] *= alpha;
    if (beta != 0.f) {
        u16x8 bb = *(const u16x8*)&base[o];
        #pragma unroll
        for (int i = 0; i < 8; ++i) acc[i] = fmaf(beta, b2f(bb[i]), acc[i]);
    }
    u16x8 r;
    #pragma unroll
    for (int i = 0; i < 8; ++i) r[i] = f2b(acc[i]);
    *(u16x8*)&out[o] = r;
}

// ---------------- MFMA 10-term GEMMs (stride-128 X rows), register-pipelined ----------------
struct GM {
    const ushort* X[10];    // pre-offset by chunk*64; row stride 128
    const ushort* Wa[10];   // pre-offset by chunk*64; row stride 128
    const ushort* Wb[10];
};

#define LOADF(tt, aa, bb)                                                          \
    {                                                                              \
        const ushort* Xp = A.X[tt];                                                \
        const ushort* Wp = gate ? A.Wb[tt] : A.Wa[tt];                             \
        _Pragma("unroll")                                                          \
        for (int ks = 0; ks < 2; ++ks) {                                           \
            _Pragma("unroll")                                                      \
            for (int mi = 0; mi < 2; ++mi)                                         \
                aa[ks][mi] = *(const bf16x8*)&Xp[(grow + mi * 16 + lr) * 128 +     \
                                                 ks * 32 + lk * 8];                \
            _Pragma("unroll")                                                      \
            for (int ni = 0; ni < 4; ++ni)                                         \
                bb[ks][ni] = *(const bf16x8*)&Wp[(ni * 16 + lr) * 128 +            \
                                                 ks * 32 + lk * 8];                \
        }                                                                          \
    }

#define MFMAF(aa, bb)                                                              \
    _Pragma("unroll")                                                              \
    for (int ks = 0; ks < 2; ++ks)                                                 \
        _Pragma("unroll")                                                          \
        for (int mi = 0; mi < 2; ++mi)                                             \
            _Pragma("unroll")                                                      \
            for (int ni = 0; ni < 4; ++ni)                                         \
                acc[mi][ni] = __builtin_amdgcn_mfma_f32_16x16x32_bf16(             \
                    aa[ks][mi], bb[ks][ni], acc[mi][ni], 0, 0, 0);

// dual gate: 64 rows/block, 4 waves (gate x 32-row half)
// gate0 -> Z[row*64+c] = sigmoid; gate1 -> xh[row*128+64+c] = bf16(sigmoid*h)
template<int NT>
__global__ __launch_bounds__(256) void mfma_dual(GM A,
        const float* __restrict__ bzp, const float* __restrict__ brp,
        const float* __restrict__ h,
        float* __restrict__ Z, ushort* __restrict__ xh) {
    int lane = threadIdx.x & 63;
    int wid  = threadIdx.x >> 6;
    int gate = wid >> 1;
    long grow = (long)blockIdx.x * 64 + (long)(wid & 1) * 32;
    int lr = lane & 15;
    int lk = lane >> 4;
    f32x4 acc[2][4];
    #pragma unroll
    for (int i = 0; i < 2; ++i)
        #pragma unroll
        for (int j = 0; j < 4; ++j)
            acc[i][j] = (f32x4){0.f, 0.f, 0.f, 0.f};

    bf16x8 a0[2][2], b0[2][4], a1[2][2], b1[2][4];
    LOADF(0, a0, b0);
    #pragma unroll
    for (int tt = 0; tt < NT; tt += 2) {
        if (tt + 1 < NT) LOADF(tt + 1, a1, b1);
        MFMAF(a0, b0);
        if (tt + 2 < NT) LOADF(tt + 2, a0, b0);
        if (tt + 1 < NT) MFMAF(a1, b1);
    }

    const float* bias = gate ? brp : bzp;
    #pragma unroll
    for (int mi = 0; mi < 2; ++mi) {
        #pragma unroll
        for (int q = 0; q < 4; ++q) {
            long row = grow + mi * 16 + lk * 4 + q;
            int n = (int)(row >> 3), b = (int)(row & 7);
            #pragma unroll
            for (int ni = 0; ni < 4; ++ni) {
                int colc = ni * 16 + lr;
                float v = acc[mi][ni][q] + bias[colc];
                float sg = 1.f / (1.f + expf(-v));
                if (gate == 0) {
                    Z[row * 64 + colc] = sg;
                } else {
                    float hv = h[((long)b * NN + n) * 64 + colc];
                    xh[row * 128 + 64 + colc] = f2b(sg * hv);
                }
            }
        }
    }
}

// single gate (H): 64 rows/block, 2 waves; fused GRU blend epilogue
template<int NT>
__global__ __launch_bounds__(128) void mfma_single(GM A,
        const float* __restrict__ bhp, const float* __restrict__ h,
        const float* __restrict__ Zg,
        float* __restrict__ outF, ushort* __restrict__ xh, int writeF) {
    int lane = threadIdx.x & 63;
    int wid  = threadIdx.x >> 6;
    const int gate = 0;
    long grow = (long)blockIdx.x * 64 + (long)wid * 32;
    int lr = lane & 15;
    int lk = lane >> 4;
    f32x4 acc[2][4];
    #pragma unroll
    for (int i = 0; i < 2; ++i)
        #pragma unroll
        for (int j = 0; j < 4; ++j)
            acc[i][j] = (f32x4){0.f, 0.f, 0.f, 0.f};

    bf16x8 a0[2][2], b0[2][4], a1[2][2], b1[2][4];
    LOADF(0, a0, b0);
    #pragma unroll
    for (int tt = 0; tt < NT; tt += 2) {
        if (tt + 1 < NT) LOADF(tt + 1, a1, b1);
        MFMAF(a0, b0);
        if (tt + 2 < NT) LOADF(tt + 2, a0, b0);
        if (tt + 1 < NT) MFMAF(a1, b1);
    }

    #pragma unroll
    for (int mi = 0; mi < 2; ++mi) {
        #pragma unroll
        for (int q = 0; q < 4; ++q) {
            long row = grow + mi * 16 + lk * 4 + q;
            int n = (int)(row >> 3), b = (int)(row & 7);
            #pragma unroll
            for (int ni = 0; ni < 4; ++ni) {
                int colc = ni * 16 + lr;
                float v = acc[mi][ni][q] + bhp[colc];
                float ht = tanhf(v);
                float z = Zg[row * 64 + colc];
                float hv = h[((long)b * NN + n) * 64 + colc];
                float res = z * hv + (1.f - z) * ht;
                if (writeF) outF[row * 64 + colc] = res;
                else        xh[row * 128 + colc] = f2b(res);
            }
        }
    }
}

// ---------------- final projection 64 -> 32 (permuted input rows) ----------------
__global__ void proj_kernel(const float* __restrict__ last, const float* __restrict__ W,
                            const float* __restrict__ bias, float* __restrict__ out) {
    long t = (long)blockIdx.x * blockDim.x + threadIdx.x;
    if (t >= (long)ROWS * OUTD) return;
    long row = t >> 5;              // n*8 + b
    int  o   = (int)(t & 31);
    int n = (int)(row >> 3), b = (int)(row & 7);
    float acc = bias[o];
    #pragma unroll
    for (int hh = 0; hh < HIDD; ++hh)
        acc = fmaf(last[row * 64 + hh], W[hh * OUTD + o], acc);
    out[((long)b * NN + n) * 32 + o] = acc;
}

extern "C" void kernel_launch(void* const* d_in, const int* in_sizes, int n_in,
                              void* d_out, int out_size, void* d_ws, size_t ws_size,
                              hipStream_t stream) {
    const float* edge_weight = (const float*)d_in[0];
    const float* hidden      = (const float*)d_in[1];
    const float* go_input    = (const float*)d_in[2];
    const float* Wz = (const float*)d_in[3];
    const float* bz = (const float*)d_in[4];
    const float* Wr = (const float*)d_in[5];
    const float* br = (const float*)d_in[6];
    const float* Wh = (const float*)d_in[7];
    const float* bh = (const float*)d_in[8];
    const float* projW = (const float*)d_in[9];
    const float* projb = (const float*)d_in[10];
    const int*   eidx  = (const int*)d_in[11];
    const int* src = eidx;
    const int* dst = eidx + NE;
    float* out = (float*)d_out;

    // ---- workspace ----
    char* p = (char*)d_ws;
    auto alloc = [&](size_t bytes) { char* r = p; p += (bytes + 15) & ~(size_t)15; return r; };
    float* deg_out = (float*)alloc(NN * 4);
    float* deg_in  = (float*)alloc(NN * 4);
    int*   cnt_f   = (int*)alloc(NN * 4);
    int*   cnt_r   = (int*)alloc(NN * 4);
    int*   off_f   = (int*)alloc((NN + 4) * 4);
    int*   off_r   = (int*)alloc((NN + 4) * 4);
    int*   pos_f   = (int*)alloc(NN * 4);
    int*   pos_r   = (int*)alloc(NN * 4);
    int*   col_f   = (int*)alloc(NE * 4);
    float* w_f     = (float*)alloc(NE * 4);
    int*   col_r   = (int*)alloc(NE * 4);
    float* w_r     = (float*)alloc(NE * 4);
    ushort* Wt     = (ushort*)alloc((size_t)2 * 3 * 2 * 3 * 64 * 128 * 2);
    const size_t XB = (size_t)ROWS * 128 * 2;   // 20.48 MB (128-wide bf16)
    ushort* xh  = (ushort*)alloc(XB);
    ushort* Tf1 = (ushort*)alloc(XB);
    ushort* Tf2 = (ushort*)alloc(XB);
    ushort* Tr1 = (ushort*)alloc(XB);
    ushort* Tr2 = (ushort*)alloc(XB);
    float*  Zbuf = (float*)alloc((size_t)ROWS * HIDD * 4);
    if ((size_t)(p - (char*)d_ws) > ws_size) return;

    const int TB = 256;
    const int EGRID = (NE + TB - 1) / TB;
    const dim3 PG(NN, 2);

    // ---- CSR build ----
    zero_kernel<<<(4 * NN + TB - 1) / TB, TB, 0, stream>>>((int*)deg_out, 4 * NN);
    deg_cnt_kernel<<<EGRID, TB, 0, stream>>>(edge_weight, src, dst, deg_out, deg_in, cnt_f, cnt_r);
    scan_kernel<<<1, 256, 0, stream>>>(cnt_f, off_f);
    scan_kernel<<<1, 256, 0, stream>>>(cnt_r, off_r);
    copy_pos_kernel<<<(NN + TB - 1) / TB, TB, 0, stream>>>(off_f, off_r, pos_f, pos_r);
    fill_kernel<<<EGRID, TB, 0, stream>>>(edge_weight, src, dst, deg_out, deg_in,
                                          pos_f, pos_r, col_f, w_f, col_r, w_r);

    convW_kernel<<<2304, 256, 0, stream>>>(Wz, Wr, Wh, Wt);
    convX_perm<<<5000, 256, 0, stream>>>((const float4*)go_input, xh, 0);

    auto wt_term = [&](int l, int g, int d, int k, int c) -> const ushort* {
        return Wt + ((((long)((l * 3 + g) * 2 + d) * 3 + k) * 64) * 128) + (long)c * 64;
    };
    const int dd[5]  = {0, 0, 0, 1, 1};
    const int kk2[5] = {0, 1, 2, 1, 2};

    for (int l = 0; l < NL; ++l) {
        const float* h = hidden + (long)l * ROWS * HIDD;
        convX_perm<<<5000, 256, 0, stream>>>((const float4*)h, xh, 1);

        // xh diffusion (both chunks at once, fwd+rev)
        prop_full<<<PG, 128, 0, stream>>>(xh, xh, nullptr,
            off_f, col_f, w_f, off_r, col_r, w_r, Tf1, Tr1, 1.f, 0.f);
        prop_full<<<PG, 128, 0, stream>>>(Tf1, Tr1, xh,
            off_f, col_f, w_f, off_r, col_r, w_r, Tf2, Tr2, 2.f, -1.f);

        const ushort* xs[5] = {xh, Tf1, Tf2, Tr1, Tr2};
        GM A{};
        for (int i = 0; i < 5; ++i) {
            A.X[i]      = xs[i];
            A.X[5 + i]  = xs[i] + 64;
            A.Wa[i]     = wt_term(l, 0, dd[i], kk2[i], 0);
            A.Wa[5 + i] = wt_term(l, 0, dd[i], kk2[i], 1);
            A.Wb[i]     = wt_term(l, 1, dd[i], kk2[i], 0);
            A.Wb[5 + i] = wt_term(l, 1, dd[i], kk2[i], 1);
        }
        mfma_dual<10><<<ROWS / 64, 256, 0, stream>>>(A, bz + l * HIDD, br + l * HIDD,
                                                     h, Zbuf, xh);

        // rh diffusion into the chunk-1 halves (rh lives in xh chunk1)
        prop_half<<<PG, 64, 0, stream>>>(xh, xh, nullptr,
            off_f, col_f, w_f, off_r, col_r, w_r, Tf1, Tr1, 1.f, 0.f);
        prop_half<<<PG, 64, 0, stream>>>(Tf1, Tr1, xh,
            off_f, col_f, w_f, off_r, col_r, w_r, Tf2, Tr2, 2.f, -1.f);

        GM Ah{};
        for (int i = 0; i < 5; ++i) {
            Ah.X[i]      = xs[i];
            Ah.X[5 + i]  = xs[i] + 64;
            Ah.Wa[i]     = wt_term(l, 2, dd[i], kk2[i], 0);
            Ah.Wa[5 + i] = wt_term(l, 2, dd[i], kk2[i], 1);
        }
        mfma_single<10><<<ROWS / 64, 128, 0, stream>>>(Ah, bh + l * HIDD, h, Zbuf,
                                                       Zbuf, xh, (l == NL - 1) ? 1 : 0);
    }

    proj_kernel<<<(int)(((long)ROWS * OUTD + TB - 1) / TB), TB, 0, stream>>>(
        Zbuf, projW, projb, out);
}